// Round 7
// baseline (129.280 us; speedup 1.0000x reference)
//
#include <hip/hip_runtime.h>

#define B_ 8
#define DIM_ 512
#define HEADS_ 8
#define HD_ 64
#define HW_ 1024
#define L_ 77
#define LP_ 80
#define CTX_ 768
#define KV_ 1101
#define KVP_ 1152
// internal KV order: self-attn rows [0,1024), context rows [1024,1101), pad [1101,1152)
#define CTX0_ 1024
// sqrt(SCALE^2 * log2(e)) folded into both q and k: 64^-0.25 * sqrt(1.4426950409)
#define SC_QK 0.42466089f

typedef __attribute__((ext_vector_type(8))) short bf16x8;
typedef __attribute__((ext_vector_type(4))) float f32x4;
typedef __attribute__((ext_vector_type(4))) unsigned short u16x4;

__device__ __forceinline__ unsigned short f2bf(float f) {
  union { float f; unsigned int u; } c; c.f = f;
  unsigned int u = c.u;
  return (unsigned short)((u + 0x7fffu + ((u >> 16) & 1u)) >> 16);
}
__device__ __forceinline__ float bf2f(unsigned short h) {
  union { unsigned int u; float f; } c; c.u = ((unsigned int)h) << 16;
  return c.f;
}

#define GLD_LDS16(gsrc, ldst) \
  __builtin_amdgcn_global_load_lds((const __attribute__((address_space(1))) void*)(gsrc), \
                                   (__attribute__((address_space(3))) void*)(ldst), 16, 0, 0)

// ---------------- converts ----------------
__global__ __launch_bounds__(256) void conv_bf16_k(const float* __restrict__ src,
                                                   unsigned short* __restrict__ dst, int n4) {
  int i = blockIdx.x * 256 + threadIdx.x;
  if (i >= n4) return;
  float4 v = *(const float4*)(src + (size_t)i * 4);
  u16x4 o;
  o[0] = f2bf(v.x); o[1] = f2bf(v.y); o[2] = f2bf(v.z); o[3] = f2bf(v.w);
  *(u16x4*)(dst + (size_t)i * 4) = o;
}

__global__ __launch_bounds__(256) void conv_ctx_k(const float* __restrict__ ctx,
                                                  unsigned short* __restrict__ dst) {
  int i = blockIdx.x * 256 + threadIdx.x;
  int total4 = B_ * LP_ * CTX_ / 4;
  if (i >= total4) return;
  int idx = i * 4;
  int b = idx / (LP_ * CTX_);
  int rem = idx - b * (LP_ * CTX_);
  int l = rem / CTX_;
  int c = rem - l * CTX_;
  float4 v = make_float4(0.f, 0.f, 0.f, 0.f);
  if (l < L_) v = *(const float4*)&ctx[((size_t)b * L_ + l) * CTX_ + c];
  u16x4 o;
  o[0] = f2bf(v.x); o[1] = f2bf(v.y); o[2] = f2bf(v.z); o[3] = f2bf(v.w);
  *(u16x4*)(dst + idx) = o;
}

// zero the KV pad rows (1101..1151)
__global__ __launch_bounds__(256) void pad_zero_k(unsigned short* __restrict__ k_s,
                                                  unsigned short* __restrict__ vT) {
  int i = blockIdx.x * 256 + threadIdx.x;
  const int total = 64 * (KVP_ - KV_) * 64;
  if (i >= total) return;
  int bh = i / ((KVP_ - KV_) * 64);
  int rem = i - bh * ((KVP_ - KV_) * 64);
  int row = KV_ + rem / 64;
  int d = rem & 63;
  k_s[((size_t)bh * KVP_ + row) * HD_ + d] = 0;
  vT[((size_t)bh * HD_ + d) * KVP_ + row] = 0;
}

// ---------------- groupnorm (fused stats+normalize+transpose) ----------------
__global__ __launch_bounds__(256) void gnorm_k(const float* __restrict__ x,
                                               const float* __restrict__ gamma,
                                               const float* __restrict__ beta,
                                               unsigned short* __restrict__ xn_t) {
  __shared__ unsigned short xs[16][1032];
  __shared__ float red[8];
  const int tid = threadIdx.x;
  const int b = blockIdx.x >> 5, g = blockIdx.x & 31;
  const float* xp = x + ((size_t)b * DIM_ + g * 16) * HW_;
  float sum = 0.f, ssq = 0.f;
#pragma unroll
  for (int i = 0; i < 16; ++i) {
    float4 v = *(const float4*)&xp[i * HW_ + tid * 4];
    sum += v.x + v.y + v.z + v.w;
    ssq += v.x * v.x + v.y * v.y + v.z * v.z + v.w * v.w;
    xs[i][tid * 4 + 0] = f2bf(v.x);
    xs[i][tid * 4 + 1] = f2bf(v.y);
    xs[i][tid * 4 + 2] = f2bf(v.z);
    xs[i][tid * 4 + 3] = f2bf(v.w);
  }
#pragma unroll
  for (int off = 32; off >= 1; off >>= 1) {
    sum += __shfl_xor(sum, off, 64);
    ssq += __shfl_xor(ssq, off, 64);
  }
  if ((tid & 63) == 0) { red[(tid >> 6) * 2] = sum; red[(tid >> 6) * 2 + 1] = ssq; }
  __syncthreads();
  sum = red[0] + red[2] + red[4] + red[6];
  ssq = red[1] + red[3] + red[5] + red[7];
  float mu = sum * (1.f / 16384.f);
  float rstd = rsqrtf(ssq * (1.f / 16384.f) - mu * mu + 1e-5f);
  float a[16], c[16];
#pragma unroll
  for (int ci = 0; ci < 16; ++ci) {
    float gm = gamma[g * 16 + ci], bt = beta[g * 16 + ci];
    a[ci] = rstd * gm;
    c[ci] = bt - mu * rstd * gm;
  }
#pragma unroll
  for (int t = 0; t < 4; ++t) {
    int hw = tid + t * 256;
    unsigned short tmp[16];
#pragma unroll
    for (int ci = 0; ci < 16; ++ci)
      tmp[ci] = f2bf(bf2f(xs[ci][hw]) * a[ci] + c[ci]);
    unsigned int w[8];
#pragma unroll
    for (int j = 0; j < 8; ++j) w[j] = (unsigned int)tmp[2 * j] | ((unsigned int)tmp[2 * j + 1] << 16);
    unsigned short* dptr = &xn_t[((size_t)b * HW_ + hw) * DIM_ + g * 16];
    *(uint4*)dptr = make_uint4(w[0], w[1], w[2], w[3]);
    *(uint4*)(dptr + 8) = make_uint4(w[4], w[5], w[6], w[7]);
  }
}

// ---------------- GEMM: C[m][n] = sum_k A[m][k]*Bt[n][k] ----------------
// BM x BN tiles, 2x2 waves, dbuf LDS 2-phase, T2 XOR chunk-swizzle on stage
// source + LDS reads (conflict-free ds_read_b128).
// MODE 0: qkv -> LDS-transpose epilogue, coalesced q/k/v stores (+bias, SC_QK)
// MODE 1: ckv -> scalar scatter to k_s/vT at rows 1024+l
// MODE 2: proj -> out = acc + bias[row] + x (residual), coalesced f32
template <int MODE, int BM, int BN>
__global__ __launch_bounds__(256, 2) void gemm_bt_k(const unsigned short* __restrict__ A,
                                                    const unsigned short* __restrict__ Bt,
                                                    int M, int N, int K,
                                                    const float* __restrict__ bias,
                                                    unsigned short* __restrict__ out_q,
                                                    unsigned short* __restrict__ out_k,
                                                    unsigned short* __restrict__ out_v,
                                                    const float* __restrict__ xres,
                                                    float* __restrict__ outf) {
  constexpr int MR = BM / 32;
  constexpr int NR = BN / 32;
  __shared__ unsigned short sm[2 * (BM + BN) * 64];
  unsigned short* As0 = sm;                 // [2][BM*64]
  unsigned short* Bs0 = sm + 2 * BM * 64;   // [2][BN*64]
  const int tid = threadIdx.x;
  const int wid = tid >> 6, lane = tid & 63;
  const int lr = lane & 15, lg = lane >> 4;
  int bid = blockIdx.x;
  // MODE 0: co-locate same-tm (A-panel-sharing) blocks on one XCD (768 = 8*96)
  if (MODE == 0) bid = (bid & 7) * 96 + (bid >> 3);
  const int ntn = N / BN;
  const int tm = bid / ntn, tn = bid - tm * ntn;
  const int m0 = tm * BM, n0 = tn * BN;
  const int wr = wid >> 1, wc = wid & 1;
  f32x4 acc[MR][NR] = {};
  const int nkt = K >> 6;

  auto stage = [&](int bi, int kk) {
#pragma unroll
    for (int i = 0; i < BM / 32; ++i) {
      int c = i * 256 + tid;
      int row = c >> 3, ch = (c & 7) ^ (row & 7);
      GLD_LDS16(A + (size_t)(m0 + row) * K + kk + ch * 8,
                As0 + (size_t)bi * BM * 64 + (size_t)(i * 256 + wid * 64) * 8);
    }
#pragma unroll
    for (int i = 0; i < BN / 32; ++i) {
      int c = i * 256 + tid;
      int row = c >> 3, ch = (c & 7) ^ (row & 7);
      GLD_LDS16(Bt + (size_t)(n0 + row) * K + kk + ch * 8,
                Bs0 + (size_t)bi * BN * 64 + (size_t)(i * 256 + wid * 64) * 8);
    }
  };

  stage(0, 0);
  __syncthreads();
  for (int kt = 0; kt < nkt; ++kt) {
    if (kt + 1 < nkt) stage((kt + 1) & 1, (kt + 1) << 6);
    const unsigned short* Ab = As0 + (kt & 1) * BM * 64;
    const unsigned short* Bb = Bs0 + (kt & 1) * BN * 64;
#pragma unroll
    for (int ks = 0; ks < 2; ++ks) {
      bf16x8 af[MR], bf[NR];
#pragma unroll
      for (int mi = 0; mi < MR; ++mi)
        af[mi] = *(const bf16x8*)&Ab[(wr * (BM / 2) + mi * 16 + lr) * 64 +
                                     (((ks * 4 + lg) ^ (lr & 7)) * 8)];
#pragma unroll
      for (int nj = 0; nj < NR; ++nj)
        bf[nj] = *(const bf16x8*)&Bb[(wc * (BN / 2) + nj * 16 + lr) * 64 +
                                     (((ks * 4 + lg) ^ (lr & 7)) * 8)];
#pragma unroll
      for (int mi = 0; mi < MR; ++mi)
#pragma unroll
        for (int nj = 0; nj < NR; ++nj)
          acc[mi][nj] = __builtin_amdgcn_mfma_f32_16x16x32_bf16(af[mi], bf[nj], acc[mi][nj], 0, 0, 0);
    }
    __syncthreads();
  }

  if constexpr (MODE == 0) {
    const int which = n0 >> 9;         // uniform per block: 0=q 1=k 2=v
    const int bb = m0 >> 10;
    const int qibase = m0 & 1023;
    if (which == 2) {
      // transpose v through LDS: logical [col 128][qi-chunk 32] of uint2 (4 bf16)
      uint2* Vt = (uint2*)sm;
#pragma unroll
      for (int mi = 0; mi < MR; ++mi) {
#pragma unroll
        for (int nj = 0; nj < NR; ++nj) {
          int col = wc * 64 + nj * 16 + lr;
          float b = bias[n0 + col];
          unsigned int w0, w1;
          float v0 = acc[mi][nj][0] + b, v1 = acc[mi][nj][1] + b;
          float v2 = acc[mi][nj][2] + b, v3 = acc[mi][nj][3] + b;
          asm("v_cvt_pk_bf16_f32 %0, %1, %2" : "=v"(w0) : "v"(v0), "v"(v1));
          asm("v_cvt_pk_bf16_f32 %0, %1, %2" : "=v"(w1) : "v"(v2), "v"(v3));
          int chunk = (wr * 16 + mi * 4 + lg) ^ (lr * 2);
          Vt[col * 32 + chunk] = make_uint2(w0, w1);
        }
      }
      __syncthreads();
#pragma unroll
      for (int it = 0; it < 8; ++it) {
        int col = wid * 32 + it * 4 + lg;
        uint4 val = *(uint4*)&Vt[col * 32 + ((lr * 2) ^ ((col & 15) * 2))];
        int colg = n0 + col;
        int head = (colg >> 6) & 7, d = colg & 63;
        *(uint4*)&out_v[(((size_t)bb * HEADS_ + head) * HD_ + d) * KVP_ + qibase + lr * 8] = val;
      }
    } else {
      // q/k: [qi 128][col 128 (+4 pad)] in LDS, then coalesced 16B row stores
      unsigned short* Tq = sm;
#pragma unroll
      for (int mi = 0; mi < MR; ++mi) {
#pragma unroll
        for (int nj = 0; nj < NR; ++nj) {
          int col = wc * 64 + nj * 16 + lr;
          float b = bias[n0 + col];
          int qr = wr * 64 + mi * 16 + lg * 4;
#pragma unroll
          for (int r = 0; r < 4; ++r)
            Tq[(qr + r) * 132 + col] = f2bf((acc[mi][nj][r] + b) * SC_QK);
        }
      }
      __syncthreads();
#pragma unroll
      for (int it = 0; it < 8; ++it) {
        int qi = wid * 32 + it * 4 + lg;
        uint2 lo = *(uint2*)&Tq[qi * 132 + lr * 8];
        uint2 hi = *(uint2*)&Tq[qi * 132 + lr * 8 + 4];
        uint4 val = make_uint4(lo.x, lo.y, hi.x, hi.y);
        int colg = n0 + lr * 8;
        int head = (colg >> 6) & 7, d = colg & 63;
        size_t bh = (size_t)bb * HEADS_ + head;
        if (which == 0)
          *(uint4*)&out_q[(bh * HW_ + qibase + qi) * HD_ + d] = val;
        else
          *(uint4*)&out_k[(bh * KVP_ + qibase + qi) * HD_ + d] = val;
      }
    }
  } else {
#pragma unroll
    for (int mi = 0; mi < MR; ++mi) {
#pragma unroll
      for (int nj = 0; nj < NR; ++nj) {
#pragma unroll
        for (int r = 0; r < 4; ++r) {
          int row = m0 + wr * (BM / 2) + mi * 16 + lg * 4 + r;
          int col = n0 + wc * (BN / 2) + nj * 16 + lr;
          float v = acc[mi][nj][r];
          if (MODE == 1) {
            int bb = row / LP_, l = row - bb * LP_;
            if (l < L_) {
              v += bias[col];
              int which = col >> 9, head = (col >> 6) & 7, d = col & 63;
              size_t bh = (size_t)bb * HEADS_ + head;
              if (which == 0) out_k[(bh * KVP_ + CTX0_ + l) * HD_ + d] = f2bf(v * SC_QK);
              else            out_v[(bh * HD_ + d) * KVP_ + CTX0_ + l] = f2bf(v);
            }
          } else {
            size_t idx = (size_t)(col >> 10) * (DIM_ * HW_) + (size_t)row * HW_ + (col & 1023);
            outf[idx] = v + bias[row] + xres[idx];
          }
        }
      }
    }
  }
}

// ---------------- flash attention: block-cooperative LDS-staged K/V ----------------
// T4 counted-vmcnt pipeline: stage t+1 stays in flight ACROSS the barrier;
// two raw s_barriers per tile, no full vmcnt(0) drain except the last tile.
#define PSTRIDE 72

template <bool MASK>
__device__ __forceinline__ void attn_tile64(const unsigned short* __restrict__ Ksb,
                                            const unsigned short* __restrict__ Vsb,
                                            int krem,
                                            const bf16x8 (&qf)[2][2],
                                            unsigned short* __restrict__ Pw0,
                                            unsigned short* __restrict__ Pw1,
                                            int lr, int lg,
                                            const int (&ro)[4], const int (&koff)[2],
                                            float (&mrun)[2], float (&lrun)[2],
                                            f32x4 (&acc)[2][4]) {
  f32x4 st[2][4] = {};
#pragma unroll
  for (int ks = 0; ks < 2; ++ks) {
    bf16x8 kf[4];
#pragma unroll
    for (int t = 0; t < 4; ++t)
      kf[t] = *(const bf16x8*)&Ksb[ro[t] + koff[ks]];
#pragma unroll
    for (int t = 0; t < 4; ++t) {
      st[0][t] = __builtin_amdgcn_mfma_f32_16x16x32_bf16(kf[t], qf[0][ks], st[0][t], 0, 0, 0);
      st[1][t] = __builtin_amdgcn_mfma_f32_16x16x32_bf16(kf[t], qf[1][ks], st[1][t], 0, 0, 0);
    }
  }
  if (MASK) {
#pragma unroll
    for (int c = 0; c < 2; ++c)
#pragma unroll
      for (int t = 0; t < 4; ++t)
#pragma unroll
        for (int r = 0; r < 4; ++r)
          st[c][t][r] = (t * 16 + lg * 4 + r < krem) ? st[c][t][r] : -INFINITY;
  }
#pragma unroll
  for (int c = 0; c < 2; ++c) {
    float t0 = fmaxf(fmaxf(st[c][0][0], st[c][0][1]), fmaxf(st[c][0][2], st[c][0][3]));
    float t1 = fmaxf(fmaxf(st[c][1][0], st[c][1][1]), fmaxf(st[c][1][2], st[c][1][3]));
    float t2 = fmaxf(fmaxf(st[c][2][0], st[c][2][1]), fmaxf(st[c][2][2], st[c][2][3]));
    float t3 = fmaxf(fmaxf(st[c][3][0], st[c][3][1]), fmaxf(st[c][3][2], st[c][3][3]));
    float mx = fmaxf(fmaxf(t0, t1), fmaxf(t2, t3));
    mx = fmaxf(mx, __shfl_xor(mx, 16, 64));
    mx = fmaxf(mx, __shfl_xor(mx, 32, 64));
    if (!__all(mx <= mrun[c] + 8.f)) {
      float mn = fmaxf(mrun[c], mx);
      float al = exp2f(mrun[c] - mn);
      lrun[c] *= al;
#pragma unroll
      for (int dt = 0; dt < 4; ++dt)
#pragma unroll
        for (int r = 0; r < 4; ++r) acc[c][dt][r] *= al;
      mrun[c] = mn;
    }
#pragma unroll
    for (int t = 0; t < 4; ++t)
#pragma unroll
      for (int r = 0; r < 4; ++r) st[c][t][r] = exp2f(st[c][t][r] - mrun[c]);
    float s0 = (st[c][0][0] + st[c][0][1]) + (st[c][0][2] + st[c][0][3]);
    float s1 = (st[c][1][0] + st[c][1][1]) + (st[c][1][2] + st[c][1][3]);
    float s2 = (st[c][2][0] + st[c][2][1]) + (st[c][2][2] + st[c][2][3]);
    float s3 = (st[c][3][0] + st[c][3][1]) + (st[c][3][2] + st[c][3][3]);
    float rs = (s0 + s1) + (s2 + s3);
    rs += __shfl_xor(rs, 16, 64);
    rs += __shfl_xor(rs, 32, 64);
    lrun[c] += rs;
    unsigned short* Pw = c ? Pw1 : Pw0;
#pragma unroll
    for (int t = 0; t < 4; ++t) {
      unsigned int w0, w1;
      asm("v_cvt_pk_bf16_f32 %0, %1, %2" : "=v"(w0) : "v"(st[c][t][0]), "v"(st[c][t][1]));
      asm("v_cvt_pk_bf16_f32 %0, %1, %2" : "=v"(w1) : "v"(st[c][t][2]), "v"(st[c][t][3]));
      *(uint2*)&Pw[lr * PSTRIDE + t * 16 + lg * 4] = make_uint2(w0, w1);
    }
  }
#pragma unroll
  for (int ks = 0; ks < 2; ++ks) {
    bf16x8 pb0 = *(const bf16x8*)&Pw0[lr * PSTRIDE + ks * 32 + lg * 8];
    bf16x8 pb1 = *(const bf16x8*)&Pw1[lr * PSTRIDE + ks * 32 + lg * 8];
#pragma unroll
    for (int dt = 0; dt < 4; ++dt) {
      bf16x8 vf = *(const bf16x8*)&Vsb[ro[dt] + koff[ks]];
      acc[0][dt] = __builtin_amdgcn_mfma_f32_16x16x32_bf16(vf, pb0, acc[0][dt], 0, 0, 0);
      acc[1][dt] = __builtin_amdgcn_mfma_f32_16x16x32_bf16(vf, pb1, acc[1][dt], 0, 0, 0);
    }
  }
}

__global__ __launch_bounds__(256, 2) void attn_k(const unsigned short* __restrict__ q_s,
                                                 const unsigned short* __restrict__ k_s,
                                                 const unsigned short* __restrict__ vT,
                                                 unsigned short* __restrict__ at_s) {
  __shared__ unsigned short Ks[2][4096];
  __shared__ unsigned short Vs[2][4096];
  __shared__ unsigned short Pb[4][2][16 * PSTRIDE];
  const int tid = threadIdx.x;
  const int wid = tid >> 6, lane = tid & 63;
  const int lr = lane & 15, lg = lane >> 4;
  const int bidx = blockIdx.x;
  const int xcd = bidx & 7, idx = bidx >> 3;
  const int bh = xcd + 8 * (idx >> 3);
  const int qt = idx & 7;
  const int q0 = qt * 128 + wid * 32;
  const unsigned short* qp = q_s + (size_t)bh * HW_ * HD_;
  const unsigned short* kp = k_s + (size_t)bh * KVP_ * HD_;
  const unsigned short* vp = vT + (size_t)bh * HD_ * KVP_;
  unsigned short* Pw0 = Pb[wid][0];
  unsigned short* Pw1 = Pb[wid][1];

  const int srow = lane >> 3;
  const int schunk = (lane & 7) ^ srow;

  // one stage = exactly 4 gload_lds per wave (vmcnt counting relies on this)
  auto stage = [&](int bufi, int kk) {
#pragma unroll
    for (int jj = 0; jj < 2; ++jj) {
      GLD_LDS16(kp + (size_t)(kk + wid * 16 + jj * 8 + srow) * HD_ + schunk * 8,
                &Ks[bufi][(wid * 2 + jj) * 512]);
      GLD_LDS16(vp + (size_t)(wid * 16 + jj * 8 + srow) * KVP_ + kk + schunk * 8,
                &Vs[bufi][(wid * 2 + jj) * 512]);
    }
  };

  int ro[4], koff[2];
#pragma unroll
  for (int t = 0; t < 4; ++t) ro[t] = (t * 16 + lr) * 64;
#pragma unroll
  for (int ks = 0; ks < 2; ++ks) koff[ks] = ((ks * 4 + lg) ^ (lr & 7)) * 8;

  bf16x8 qf[2][2];
#pragma unroll
  for (int c = 0; c < 2; ++c)
#pragma unroll
    for (int ks = 0; ks < 2; ++ks)
      qf[c][ks] = *(const bf16x8*)&qp[(size_t)(q0 + c * 16 + lr) * HD_ + ks * 32 + lg * 8];

  f32x4 acc[2][4] = {};
  float mrun[2] = {-INFINITY, -INFINITY};
  float lrun[2] = {0.f, 0.f};

  // prologue: q loads, then stage(0), stage(1) — issue order pinned so the
  // counted vmcnt at loop head retires {qf, stage0} and leaves stage1 in flight
  __builtin_amdgcn_sched_barrier(0);
  stage(0, 0);
  __builtin_amdgcn_sched_barrier(0);
  stage(1, 64);
  __builtin_amdgcn_sched_barrier(0);

  int cur = 0;
  for (int it = 0; it < 17; ++it) {
    // stage(it) landed (mine); stage(it+1) stays in flight across the barrier
    asm volatile("s_waitcnt vmcnt(4)" ::: "memory");
    __builtin_amdgcn_sched_barrier(0);
    __builtin_amdgcn_s_barrier();
    __builtin_amdgcn_sched_barrier(0);
    attn_tile64<false>(Ks[cur], Vs[cur], 64, qf, Pw0, Pw1, lr, lg, ro, koff, mrun, lrun, acc);
    // my LDS reads of buf[cur] have returned; after the barrier everyone's have
    asm volatile("s_waitcnt lgkmcnt(0)" ::: "memory");
    __builtin_amdgcn_sched_barrier(0);
    __builtin_amdgcn_s_barrier();
    __builtin_amdgcn_sched_barrier(0);
    if (it < 16) stage(cur, (it + 2) * 64);
    cur ^= 1;
  }
  // final tile (17): full drain, masked at KV_
  asm volatile("s_waitcnt vmcnt(0)" ::: "memory");
  __builtin_amdgcn_sched_barrier(0);
  __builtin_amdgcn_s_barrier();
  __builtin_amdgcn_sched_barrier(0);
  attn_tile64<true>(Ks[cur], Vs[cur], KV_ - 17 * 64, qf, Pw0, Pw1, lr, lg, ro, koff, mrun, lrun, acc);

  const int bb = bh >> 3, head = bh & 7;
#pragma unroll
  for (int c = 0; c < 2; ++c) {
    const float inv = 1.f / lrun[c];
    const int qi = q0 + c * 16 + lr;
#pragma unroll
    for (int dt = 0; dt < 4; ++dt) {
      u16x4 o;
#pragma unroll
      for (int r = 0; r < 4; ++r) o[r] = f2bf(acc[c][dt][r] * inv);
      *(u16x4*)&at_s[((size_t)bb * HW_ + qi) * DIM_ + head * HD_ + dt * 16 + lg * 4] = o;
    }
  }
}

extern "C" void kernel_launch(void* const* d_in, const int* in_sizes, int n_in,
                              void* d_out, int out_size, void* d_ws, size_t ws_size,
                              hipStream_t stream) {
  (void)in_sizes; (void)n_in; (void)out_size; (void)ws_size;
  const float* x      = (const float*)d_in[0];
  const float* ctx    = (const float*)d_in[1];
  const float* gng    = (const float*)d_in[2];
  const float* gnb    = (const float*)d_in[3];
  const float* qkv_w  = (const float*)d_in[4];
  const float* qkv_b  = (const float*)d_in[5];
  const float* ckv_w  = (const float*)d_in[6];
  const float* ckv_b  = (const float*)d_in[7];
  const float* proj_w = (const float*)d_in[8];
  const float* proj_b = (const float*)d_in[9];
  float* out = (float*)d_out;

  char* ws = (char*)d_ws;
  size_t off = 0;
  auto alloc = [&](size_t bytes) {
    char* p = ws + off;
    off = (off + bytes + 255) & ~(size_t)255;
    return p;
  };
  unsigned short* xn_t    = (unsigned short*)alloc((size_t)B_ * HW_ * DIM_ * 2);
  unsigned short* ctx_bf  = (unsigned short*)alloc((size_t)B_ * LP_ * CTX_ * 2);
  unsigned short* qkvw_bf = (unsigned short*)alloc((size_t)3 * DIM_ * DIM_ * 2);
  unsigned short* ckvw_bf = (unsigned short*)alloc((size_t)2 * DIM_ * CTX_ * 2);
  unsigned short* projw_bf= (unsigned short*)alloc((size_t)DIM_ * DIM_ * 2);
  unsigned short* q_s     = (unsigned short*)alloc((size_t)64 * HW_ * HD_ * 2);
  unsigned short* k_s     = (unsigned short*)alloc((size_t)64 * KVP_ * HD_ * 2);
  unsigned short* vT      = (unsigned short*)alloc((size_t)64 * HD_ * KVP_ * 2);
  unsigned short* at_s    = (unsigned short*)alloc((size_t)B_ * HW_ * DIM_ * 2);

  conv_bf16_k<<<768, 256, 0, stream>>>(qkv_w, qkvw_bf, 3 * DIM_ * DIM_ / 4);
  conv_bf16_k<<<768, 256, 0, stream>>>(ckv_w, ckvw_bf, 2 * DIM_ * CTX_ / 4);
  conv_bf16_k<<<256, 256, 0, stream>>>(proj_w, projw_bf, DIM_ * DIM_ / 4);
  conv_ctx_k<<<480, 256, 0, stream>>>(ctx, ctx_bf);
  gnorm_k<<<256, 256, 0, stream>>>(x, gng, gnb, xn_t);
  pad_zero_k<<<816, 256, 0, stream>>>(k_s, vT);
  gemm_bt_k<0, 128, 128><<<768, 256, 0, stream>>>(xn_t, qkvw_bf, 8192, 1536, 512, qkv_b,
                                                  q_s, k_s, vT, nullptr, nullptr);
  gemm_bt_k<1, 128, 128><<<40, 256, 0, stream>>>(ctx_bf, ckvw_bf, 640, 1024, 768, ckv_b,
                                                 nullptr, k_s, vT, nullptr, nullptr);
  attn_k<<<512, 256, 0, stream>>>(q_s, k_s, vT, at_s);
  gemm_bt_k<2, 64, 128><<<512, 256, 0, stream>>>(projw_bf, at_s, 512, 8192, 512, proj_b,
                                                 nullptr, nullptr, nullptr, x, out);
}

// Round 8
// 118.530 us; speedup vs baseline: 1.0907x; 1.0907x over previous
//
#include <hip/hip_runtime.h>

#define B_ 8
#define DIM_ 512
#define HEADS_ 8
#define HD_ 64
#define HW_ 1024
#define L_ 77
#define LP_ 80
#define CTX_ 768
#define KV_ 1101
#define KVP_ 1152
// internal KV order: self-attn rows [0,1024), context rows [1024,1101), pad [1101,1152)
#define CTX0_ 1024
// sqrt(SCALE^2 * log2(e)) folded into both q and k: 64^-0.25 * sqrt(1.4426950409)
#define SC_QK 0.42466089f

typedef __attribute__((ext_vector_type(8))) short bf16x8;
typedef __attribute__((ext_vector_type(4))) float f32x4;
typedef __attribute__((ext_vector_type(4))) unsigned short u16x4;

__device__ __forceinline__ unsigned short f2bf(float f) {
  union { float f; unsigned int u; } c; c.f = f;
  unsigned int u = c.u;
  return (unsigned short)((u + 0x7fffu + ((u >> 16) & 1u)) >> 16);
}
__device__ __forceinline__ float bf2f(unsigned short h) {
  union { unsigned int u; float f; } c; c.u = ((unsigned int)h) << 16;
  return c.f;
}

#define GLD_LDS16(gsrc, ldst) \
  __builtin_amdgcn_global_load_lds((const __attribute__((address_space(1))) void*)(gsrc), \
                                   (__attribute__((address_space(3))) void*)(ldst), 16, 0, 0)

// ---------------- converts ----------------
__global__ __launch_bounds__(256) void conv_bf16_k(const float* __restrict__ src,
                                                   unsigned short* __restrict__ dst, int n4) {
  int i = blockIdx.x * 256 + threadIdx.x;
  if (i >= n4) return;
  float4 v = *(const float4*)(src + (size_t)i * 4);
  u16x4 o;
  o[0] = f2bf(v.x); o[1] = f2bf(v.y); o[2] = f2bf(v.z); o[3] = f2bf(v.w);
  *(u16x4*)(dst + (size_t)i * 4) = o;
}

__global__ __launch_bounds__(256) void conv_ctx_k(const float* __restrict__ ctx,
                                                  unsigned short* __restrict__ dst) {
  int i = blockIdx.x * 256 + threadIdx.x;
  int total4 = B_ * LP_ * CTX_ / 4;
  if (i >= total4) return;
  int idx = i * 4;
  int b = idx / (LP_ * CTX_);
  int rem = idx - b * (LP_ * CTX_);
  int l = rem / CTX_;
  int c = rem - l * CTX_;
  float4 v = make_float4(0.f, 0.f, 0.f, 0.f);
  if (l < L_) v = *(const float4*)&ctx[((size_t)b * L_ + l) * CTX_ + c];
  u16x4 o;
  o[0] = f2bf(v.x); o[1] = f2bf(v.y); o[2] = f2bf(v.z); o[3] = f2bf(v.w);
  *(u16x4*)(dst + idx) = o;
}

// zero the KV pad rows (1101..1151)
__global__ __launch_bounds__(256) void pad_zero_k(unsigned short* __restrict__ k_s,
                                                  unsigned short* __restrict__ vT) {
  int i = blockIdx.x * 256 + threadIdx.x;
  const int total = 64 * (KVP_ - KV_) * 64;
  if (i >= total) return;
  int bh = i / ((KVP_ - KV_) * 64);
  int rem = i - bh * ((KVP_ - KV_) * 64);
  int row = KV_ + rem / 64;
  int d = rem & 63;
  k_s[((size_t)bh * KVP_ + row) * HD_ + d] = 0;
  vT[((size_t)bh * HD_ + d) * KVP_ + row] = 0;
}

// ---------------- groupnorm (fused stats+normalize+transpose) ----------------
__global__ __launch_bounds__(256) void gnorm_k(const float* __restrict__ x,
                                               const float* __restrict__ gamma,
                                               const float* __restrict__ beta,
                                               unsigned short* __restrict__ xn_t) {
  __shared__ unsigned short xs[16][1032];
  __shared__ float red[8];
  const int tid = threadIdx.x;
  const int b = blockIdx.x >> 5, g = blockIdx.x & 31;
  const float* xp = x + ((size_t)b * DIM_ + g * 16) * HW_;
  float sum = 0.f, ssq = 0.f;
#pragma unroll
  for (int i = 0; i < 16; ++i) {
    float4 v = *(const float4*)&xp[i * HW_ + tid * 4];
    sum += v.x + v.y + v.z + v.w;
    ssq += v.x * v.x + v.y * v.y + v.z * v.z + v.w * v.w;
    xs[i][tid * 4 + 0] = f2bf(v.x);
    xs[i][tid * 4 + 1] = f2bf(v.y);
    xs[i][tid * 4 + 2] = f2bf(v.z);
    xs[i][tid * 4 + 3] = f2bf(v.w);
  }
#pragma unroll
  for (int off = 32; off >= 1; off >>= 1) {
    sum += __shfl_xor(sum, off, 64);
    ssq += __shfl_xor(ssq, off, 64);
  }
  if ((tid & 63) == 0) { red[(tid >> 6) * 2] = sum; red[(tid >> 6) * 2 + 1] = ssq; }
  __syncthreads();
  sum = red[0] + red[2] + red[4] + red[6];
  ssq = red[1] + red[3] + red[5] + red[7];
  float mu = sum * (1.f / 16384.f);
  float rstd = rsqrtf(ssq * (1.f / 16384.f) - mu * mu + 1e-5f);
  float a[16], c[16];
#pragma unroll
  for (int ci = 0; ci < 16; ++ci) {
    float gm = gamma[g * 16 + ci], bt = beta[g * 16 + ci];
    a[ci] = rstd * gm;
    c[ci] = bt - mu * rstd * gm;
  }
#pragma unroll
  for (int t = 0; t < 4; ++t) {
    int hw = tid + t * 256;
    unsigned short tmp[16];
#pragma unroll
    for (int ci = 0; ci < 16; ++ci)
      tmp[ci] = f2bf(bf2f(xs[ci][hw]) * a[ci] + c[ci]);
    unsigned int w[8];
#pragma unroll
    for (int j = 0; j < 8; ++j) w[j] = (unsigned int)tmp[2 * j] | ((unsigned int)tmp[2 * j + 1] << 16);
    unsigned short* dptr = &xn_t[((size_t)b * HW_ + hw) * DIM_ + g * 16];
    *(uint4*)dptr = make_uint4(w[0], w[1], w[2], w[3]);
    *(uint4*)(dptr + 8) = make_uint4(w[4], w[5], w[6], w[7]);
  }
}

// ---------------- GEMM: C[m][n] = sum_k A[m][k]*Bt[n][k] ----------------
// BM x BN tiles, 2x2 waves, dbuf LDS 2-phase, T2 XOR chunk-swizzle on stage
// source + LDS reads (conflict-free ds_read_b128).
// MODE 0: qkv -> LDS-transpose epilogue, coalesced q/k/v stores (+bias, SC_QK)
// MODE 1: ckv -> scalar scatter to k_s/vT at rows 1024+l
// MODE 2: proj -> out = acc + bias[row] + x (residual), coalesced f32
template <int MODE, int BM, int BN>
__global__ __launch_bounds__(256, 2) void gemm_bt_k(const unsigned short* __restrict__ A,
                                                    const unsigned short* __restrict__ Bt,
                                                    int M, int N, int K,
                                                    const float* __restrict__ bias,
                                                    unsigned short* __restrict__ out_q,
                                                    unsigned short* __restrict__ out_k,
                                                    unsigned short* __restrict__ out_v,
                                                    const float* __restrict__ xres,
                                                    float* __restrict__ outf) {
  constexpr int MR = BM / 32;
  constexpr int NR = BN / 32;
  __shared__ unsigned short sm[2 * (BM + BN) * 64];
  unsigned short* As0 = sm;                 // [2][BM*64]
  unsigned short* Bs0 = sm + 2 * BM * 64;   // [2][BN*64]
  const int tid = threadIdx.x;
  const int wid = tid >> 6, lane = tid & 63;
  const int lr = lane & 15, lg = lane >> 4;
  int bid = blockIdx.x;
  // MODE 0: co-locate same-tm (A-panel-sharing) blocks on one XCD (768 = 8*96)
  if (MODE == 0) bid = (bid & 7) * 96 + (bid >> 3);
  const int ntn = N / BN;
  const int tm = bid / ntn, tn = bid - tm * ntn;
  const int m0 = tm * BM, n0 = tn * BN;
  const int wr = wid >> 1, wc = wid & 1;
  f32x4 acc[MR][NR] = {};
  const int nkt = K >> 6;

  auto stage = [&](int bi, int kk) {
#pragma unroll
    for (int i = 0; i < BM / 32; ++i) {
      int c = i * 256 + tid;
      int row = c >> 3, ch = (c & 7) ^ (row & 7);
      GLD_LDS16(A + (size_t)(m0 + row) * K + kk + ch * 8,
                As0 + (size_t)bi * BM * 64 + (size_t)(i * 256 + wid * 64) * 8);
    }
#pragma unroll
    for (int i = 0; i < BN / 32; ++i) {
      int c = i * 256 + tid;
      int row = c >> 3, ch = (c & 7) ^ (row & 7);
      GLD_LDS16(Bt + (size_t)(n0 + row) * K + kk + ch * 8,
                Bs0 + (size_t)bi * BN * 64 + (size_t)(i * 256 + wid * 64) * 8);
    }
  };

  stage(0, 0);
  __syncthreads();
  for (int kt = 0; kt < nkt; ++kt) {
    if (kt + 1 < nkt) stage((kt + 1) & 1, (kt + 1) << 6);
    const unsigned short* Ab = As0 + (kt & 1) * BM * 64;
    const unsigned short* Bb = Bs0 + (kt & 1) * BN * 64;
#pragma unroll
    for (int ks = 0; ks < 2; ++ks) {
      bf16x8 af[MR], bf[NR];
#pragma unroll
      for (int mi = 0; mi < MR; ++mi)
        af[mi] = *(const bf16x8*)&Ab[(wr * (BM / 2) + mi * 16 + lr) * 64 +
                                     (((ks * 4 + lg) ^ (lr & 7)) * 8)];
#pragma unroll
      for (int nj = 0; nj < NR; ++nj)
        bf[nj] = *(const bf16x8*)&Bb[(wc * (BN / 2) + nj * 16 + lr) * 64 +
                                     (((ks * 4 + lg) ^ (lr & 7)) * 8)];
#pragma unroll
      for (int mi = 0; mi < MR; ++mi)
#pragma unroll
        for (int nj = 0; nj < NR; ++nj)
          acc[mi][nj] = __builtin_amdgcn_mfma_f32_16x16x32_bf16(af[mi], bf[nj], acc[mi][nj], 0, 0, 0);
    }
    __syncthreads();
  }

  if constexpr (MODE == 0) {
    const int which = n0 >> 9;         // uniform per block: 0=q 1=k 2=v
    const int bb = m0 >> 10;
    const int qibase = m0 & 1023;
    if (which == 2) {
      // transpose v through LDS: logical [col 128][qi-chunk 32] of uint2 (4 bf16)
      uint2* Vt = (uint2*)sm;
#pragma unroll
      for (int mi = 0; mi < MR; ++mi) {
#pragma unroll
        for (int nj = 0; nj < NR; ++nj) {
          int col = wc * 64 + nj * 16 + lr;
          float b = bias[n0 + col];
          unsigned int w0, w1;
          float v0 = acc[mi][nj][0] + b, v1 = acc[mi][nj][1] + b;
          float v2 = acc[mi][nj][2] + b, v3 = acc[mi][nj][3] + b;
          asm("v_cvt_pk_bf16_f32 %0, %1, %2" : "=v"(w0) : "v"(v0), "v"(v1));
          asm("v_cvt_pk_bf16_f32 %0, %1, %2" : "=v"(w1) : "v"(v2), "v"(v3));
          int chunk = (wr * 16 + mi * 4 + lg) ^ (lr * 2);
          Vt[col * 32 + chunk] = make_uint2(w0, w1);
        }
      }
      __syncthreads();
#pragma unroll
      for (int it = 0; it < 8; ++it) {
        int col = wid * 32 + it * 4 + lg;
        uint4 val = *(uint4*)&Vt[col * 32 + ((lr * 2) ^ ((col & 15) * 2))];
        int colg = n0 + col;
        int head = (colg >> 6) & 7, d = colg & 63;
        *(uint4*)&out_v[(((size_t)bb * HEADS_ + head) * HD_ + d) * KVP_ + qibase + lr * 8] = val;
      }
    } else {
      // q/k: [qi 128][col 128 (+4 pad)] in LDS, then coalesced 16B row stores
      unsigned short* Tq = sm;
#pragma unroll
      for (int mi = 0; mi < MR; ++mi) {
#pragma unroll
        for (int nj = 0; nj < NR; ++nj) {
          int col = wc * 64 + nj * 16 + lr;
          float b = bias[n0 + col];
          int qr = wr * 64 + mi * 16 + lg * 4;
#pragma unroll
          for (int r = 0; r < 4; ++r)
            Tq[(qr + r) * 132 + col] = f2bf((acc[mi][nj][r] + b) * SC_QK);
        }
      }
      __syncthreads();
#pragma unroll
      for (int it = 0; it < 8; ++it) {
        int qi = wid * 32 + it * 4 + lg;
        uint2 lo = *(uint2*)&Tq[qi * 132 + lr * 8];
        uint2 hi = *(uint2*)&Tq[qi * 132 + lr * 8 + 4];
        uint4 val = make_uint4(lo.x, lo.y, hi.x, hi.y);
        int colg = n0 + lr * 8;
        int head = (colg >> 6) & 7, d = colg & 63;
        size_t bh = (size_t)bb * HEADS_ + head;
        if (which == 0)
          *(uint4*)&out_q[(bh * HW_ + qibase + qi) * HD_ + d] = val;
        else
          *(uint4*)&out_k[(bh * KVP_ + qibase + qi) * HD_ + d] = val;
      }
    }
  } else {
#pragma unroll
    for (int mi = 0; mi < MR; ++mi) {
#pragma unroll
      for (int nj = 0; nj < NR; ++nj) {
#pragma unroll
        for (int r = 0; r < 4; ++r) {
          int row = m0 + wr * (BM / 2) + mi * 16 + lg * 4 + r;
          int col = n0 + wc * (BN / 2) + nj * 16 + lr;
          float v = acc[mi][nj][r];
          if (MODE == 1) {
            int bb = row / LP_, l = row - bb * LP_;
            if (l < L_) {
              v += bias[col];
              int which = col >> 9, head = (col >> 6) & 7, d = col & 63;
              size_t bh = (size_t)bb * HEADS_ + head;
              if (which == 0) out_k[(bh * KVP_ + CTX0_ + l) * HD_ + d] = f2bf(v * SC_QK);
              else            out_v[(bh * HD_ + d) * KVP_ + CTX0_ + l] = f2bf(v);
            }
          } else {
            size_t idx = (size_t)(col >> 10) * (DIM_ * HW_) + (size_t)row * HW_ + (col & 1023);
            outf[idx] = v + bias[row] + xres[idx];
          }
        }
      }
    }
  }
}

// ---------------- flash attention: 8-wave blocks, 1 q-col/wave, no-max softmax ----------------
// Scores are bounded: q,k pre-scaled by SC_QK (|S_log2| << 126), so softmax uses
// p = exp2(S) directly (exact after final /sum) — no online max, no rescale.
#define PSTRIDE 72

template <bool MASK>
__device__ __forceinline__ void attn_tile64(const unsigned short* __restrict__ Ksb,
                                            const unsigned short* __restrict__ Vsb,
                                            int krem,
                                            const bf16x8 (&qf)[2],
                                            unsigned short* __restrict__ Pw,
                                            int lr, int lg,
                                            const int (&ro)[4], const int (&koff)[2],
                                            float& lrun, f32x4 (&acc)[4]) {
  f32x4 st[4] = {};
  __builtin_amdgcn_s_setprio(1);
#pragma unroll
  for (int ks = 0; ks < 2; ++ks) {
    bf16x8 kf[4];
#pragma unroll
    for (int t = 0; t < 4; ++t)
      kf[t] = *(const bf16x8*)&Ksb[ro[t] + koff[ks]];
#pragma unroll
    for (int t = 0; t < 4; ++t)
      st[t] = __builtin_amdgcn_mfma_f32_16x16x32_bf16(kf[t], qf[ks], st[t], 0, 0, 0);
  }
  __builtin_amdgcn_s_setprio(0);
  if (MASK) {
#pragma unroll
    for (int t = 0; t < 4; ++t)
#pragma unroll
      for (int r = 0; r < 4; ++r)
        st[t][r] = (t * 16 + lg * 4 + r < krem) ? st[t][r] : -INFINITY;
  }
  // p = exp2(S), no max subtraction
#pragma unroll
  for (int t = 0; t < 4; ++t)
#pragma unroll
    for (int r = 0; r < 4; ++r) st[t][r] = exp2f(st[t][r]);
  float s0 = (st[0][0] + st[0][1]) + (st[0][2] + st[0][3]);
  float s1 = (st[1][0] + st[1][1]) + (st[1][2] + st[1][3]);
  float s2 = (st[2][0] + st[2][1]) + (st[2][2] + st[2][3]);
  float s3 = (st[3][0] + st[3][1]) + (st[3][2] + st[3][3]);
  float rs = (s0 + s1) + (s2 + s3);
  rs += __shfl_xor(rs, 16, 64);
  rs += __shfl_xor(rs, 32, 64);
  lrun += rs;
  // pack P^T -> [q=lr][k] LDS
#pragma unroll
  for (int t = 0; t < 4; ++t) {
    unsigned int w0, w1;
    asm("v_cvt_pk_bf16_f32 %0, %1, %2" : "=v"(w0) : "v"(st[t][0]), "v"(st[t][1]));
    asm("v_cvt_pk_bf16_f32 %0, %1, %2" : "=v"(w1) : "v"(st[t][2]), "v"(st[t][3]));
    *(uint2*)&Pw[lr * PSTRIDE + t * 16 + lg * 4] = make_uint2(w0, w1);
  }
  // PV: O^T[d][q] += V^T[d][k] · P[q][k]
#pragma unroll
  for (int ks = 0; ks < 2; ++ks) {
    bf16x8 pb = *(const bf16x8*)&Pw[lr * PSTRIDE + ks * 32 + lg * 8];
    __builtin_amdgcn_s_setprio(1);
#pragma unroll
    for (int dt = 0; dt < 4; ++dt) {
      bf16x8 vf = *(const bf16x8*)&Vsb[ro[dt] + koff[ks]];
      acc[dt] = __builtin_amdgcn_mfma_f32_16x16x32_bf16(vf, pb, acc[dt], 0, 0, 0);
    }
    __builtin_amdgcn_s_setprio(0);
  }
}

__global__ __launch_bounds__(512, 4) void attn_k(const unsigned short* __restrict__ q_s,
                                                 const unsigned short* __restrict__ k_s,
                                                 const unsigned short* __restrict__ vT,
                                                 unsigned short* __restrict__ at_s) {
  __shared__ unsigned short Ks[2][4096];
  __shared__ unsigned short Vs[2][4096];
  __shared__ unsigned short Pb[8][16 * PSTRIDE];
  const int tid = threadIdx.x;
  const int wid = tid >> 6, lane = tid & 63;
  const int lr = lane & 15, lg = lane >> 4;
  // grid = 512: 64 bh x 8 qtiles of 128 q; XCD-bijective swizzle
  const int bidx = blockIdx.x;
  const int xcd = bidx & 7, idx = bidx >> 3;
  const int bh = xcd + 8 * (idx >> 3);
  const int qt = idx & 7;
  const int q0 = qt * 128 + wid * 16;   // one 16-q col per wave
  const unsigned short* qp = q_s + (size_t)bh * HW_ * HD_;
  const unsigned short* kp = k_s + (size_t)bh * KVP_ * HD_;
  const unsigned short* vp = vT + (size_t)bh * HD_ * KVP_;
  unsigned short* Pw = Pb[wid];

  const int srow = lane >> 3;
  const int schunk = (lane & 7) ^ srow;

  // one stage = exactly 2 gload_lds per wave (waves 0-3: K, waves 4-7: V)
  auto stage = [&](int bufi, int kk) {
    if (wid < 4) {
#pragma unroll
      for (int jj = 0; jj < 2; ++jj)
        GLD_LDS16(kp + (size_t)(kk + wid * 16 + jj * 8 + srow) * HD_ + schunk * 8,
                  &Ks[bufi][(wid * 2 + jj) * 512]);
    } else {
#pragma unroll
      for (int jj = 0; jj < 2; ++jj)
        GLD_LDS16(vp + (size_t)((wid - 4) * 16 + jj * 8 + srow) * KVP_ + kk + schunk * 8,
                  &Vs[bufi][((wid - 4) * 2 + jj) * 512]);
    }
  };

  int ro[4], koff[2];
#pragma unroll
  for (int t = 0; t < 4; ++t) ro[t] = (t * 16 + lr) * 64;
#pragma unroll
  for (int ks = 0; ks < 2; ++ks) koff[ks] = ((ks * 4 + lg) ^ (lr & 7)) * 8;

  bf16x8 qf[2];
#pragma unroll
  for (int ks = 0; ks < 2; ++ks)
    qf[ks] = *(const bf16x8*)&qp[(size_t)(q0 + lr) * HD_ + ks * 32 + lg * 8];

  f32x4 acc[4] = {};
  float lrun = 0.f;

  // prologue: pin issue order so counted vmcnt at loop head is exact
  __builtin_amdgcn_sched_barrier(0);
  stage(0, 0);
  __builtin_amdgcn_sched_barrier(0);
  stage(1, 64);
  __builtin_amdgcn_sched_barrier(0);

  int cur = 0;
  for (int it = 0; it < 17; ++it) {
    // my stage(it) loads landed; stage(it+1) stays in flight across the barrier
    asm volatile("s_waitcnt vmcnt(2)" ::: "memory");
    __builtin_amdgcn_sched_barrier(0);
    __builtin_amdgcn_s_barrier();
    __builtin_amdgcn_sched_barrier(0);
    attn_tile64<false>(Ks[cur], Vs[cur], 64, qf, Pw, lr, lg, ro, koff, lrun, acc);
    asm volatile("s_waitcnt lgkmcnt(0)" ::: "memory");
    __builtin_amdgcn_sched_barrier(0);
    __builtin_amdgcn_s_barrier();
    __builtin_amdgcn_sched_barrier(0);
    if (it < 16) stage(cur, (it + 2) * 64);
    cur ^= 1;
  }
  // final tile: full drain, masked at KV_
  asm volatile("s_waitcnt vmcnt(0)" ::: "memory");
  __builtin_amdgcn_sched_barrier(0);
  __builtin_amdgcn_s_barrier();
  __builtin_amdgcn_sched_barrier(0);
  attn_tile64<true>(Ks[cur], Vs[cur], KV_ - 17 * 64, qf, Pw, lr, lg, ro, koff, lrun, acc);

  const int bb = bh >> 3, head = bh & 7;
  const float inv = 1.f / lrun;
  const int qi = q0 + lr;
#pragma unroll
  for (int dt = 0; dt < 4; ++dt) {
    u16x4 o;
#pragma unroll
    for (int r = 0; r < 4; ++r) o[r] = f2bf(acc[dt][r] * inv);
    *(u16x4*)&at_s[((size_t)bb * HW_ + qi) * DIM_ + head * HD_ + dt * 16 + lg * 4] = o;
  }
}

extern "C" void kernel_launch(void* const* d_in, const int* in_sizes, int n_in,
                              void* d_out, int out_size, void* d_ws, size_t ws_size,
                              hipStream_t stream) {
  (void)in_sizes; (void)n_in; (void)out_size; (void)ws_size;
  const float* x      = (const float*)d_in[0];
  const float* ctx    = (const float*)d_in[1];
  const float* gng    = (const float*)d_in[2];
  const float* gnb    = (const float*)d_in[3];
  const float* qkv_w  = (const float*)d_in[4];
  const float* qkv_b  = (const float*)d_in[5];
  const float* ckv_w  = (const float*)d_in[6];
  const float* ckv_b  = (const float*)d_in[7];
  const float* proj_w = (const float*)d_in[8];
  const float* proj_b = (const float*)d_in[9];
  float* out = (float*)d_out;

  char* ws = (char*)d_ws;
  size_t off = 0;
  auto alloc = [&](size_t bytes) {
    char* p = ws + off;
    off = (off + bytes + 255) & ~(size_t)255;
    return p;
  };
  unsigned short* xn_t    = (unsigned short*)alloc((size_t)B_ * HW_ * DIM_ * 2);
  unsigned short* ctx_bf  = (unsigned short*)alloc((size_t)B_ * LP_ * CTX_ * 2);
  unsigned short* qkvw_bf = (unsigned short*)alloc((size_t)3 * DIM_ * DIM_ * 2);
  unsigned short* ckvw_bf = (unsigned short*)alloc((size_t)2 * DIM_ * CTX_ * 2);
  unsigned short* projw_bf= (unsigned short*)alloc((size_t)DIM_ * DIM_ * 2);
  unsigned short* q_s     = (unsigned short*)alloc((size_t)64 * HW_ * HD_ * 2);
  unsigned short* k_s     = (unsigned short*)alloc((size_t)64 * KVP_ * HD_ * 2);
  unsigned short* vT      = (unsigned short*)alloc((size_t)64 * HD_ * KVP_ * 2);
  unsigned short* at_s    = (unsigned short*)alloc((size_t)B_ * HW_ * DIM_ * 2);

  conv_bf16_k<<<768, 256, 0, stream>>>(qkv_w, qkvw_bf, 3 * DIM_ * DIM_ / 4);
  conv_bf16_k<<<768, 256, 0, stream>>>(ckv_w, ckvw_bf, 2 * DIM_ * CTX_ / 4);
  conv_bf16_k<<<256, 256, 0, stream>>>(proj_w, projw_bf, DIM_ * DIM_ / 4);
  conv_ctx_k<<<480, 256, 0, stream>>>(ctx, ctx_bf);
  gnorm_k<<<256, 256, 0, stream>>>(x, gng, gnb, xn_t);
  pad_zero_k<<<816, 256, 0, stream>>>(k_s, vT);
  gemm_bt_k<0, 128, 128><<<768, 256, 0, stream>>>(xn_t, qkvw_bf, 8192, 1536, 512, qkv_b,
                                                  q_s, k_s, vT, nullptr, nullptr);
  gemm_bt_k<1, 128, 128><<<40, 256, 0, stream>>>(ctx_bf, ckvw_bf, 640, 1024, 768, ckv_b,
                                                 nullptr, k_s, vT, nullptr, nullptr);
  attn_k<<<512, 512, 0, stream>>>(q_s, k_s, vT, at_s);
  gemm_bt_k<2, 64, 128><<<512, 256, 0, stream>>>(projw_bf, at_s, 512, 8192, 512, proj_b,
                                                 nullptr, nullptr, nullptr, x, out);
}

// Round 9
// 104.554 us; speedup vs baseline: 1.2365x; 1.1337x over previous
//
#include <hip/hip_runtime.h>

#define B_ 8
#define DIM_ 512
#define HEADS_ 8
#define HD_ 64
#define HW_ 1024
#define L_ 77
#define LP_ 80
#define CTX_ 768
#define KV_ 1101
#define KVP_ 1152
// internal KV order: self-attn rows [0,1024), context rows [1024,1101), pad [1101,1152)
#define CTX0_ 1024
// sqrt(SCALE^2 * log2(e)) folded into both q and k: 64^-0.25 * sqrt(1.4426950409)
#define SC_QK 0.42466089f

typedef __attribute__((ext_vector_type(8))) short bf16x8;
typedef __attribute__((ext_vector_type(4))) float f32x4;
typedef __attribute__((ext_vector_type(4))) unsigned short u16x4;

__device__ __forceinline__ unsigned short f2bf(float f) {
  union { float f; unsigned int u; } c; c.f = f;
  unsigned int u = c.u;
  return (unsigned short)((u + 0x7fffu + ((u >> 16) & 1u)) >> 16);
}
__device__ __forceinline__ float bf2f(unsigned short h) {
  union { unsigned int u; float f; } c; c.u = ((unsigned int)h) << 16;
  return c.f;
}

#define GLD_LDS16(gsrc, ldst) \
  __builtin_amdgcn_global_load_lds((const __attribute__((address_space(1))) void*)(gsrc), \
                                   (__attribute__((address_space(3))) void*)(ldst), 16, 0, 0)

// ---------------- converts ----------------
// merged f32->bf16 convert of the three weight matrices (one launch)
__global__ __launch_bounds__(256) void conv_w_k(const float* __restrict__ qkv_w,
                                                const float* __restrict__ ckv_w,
                                                const float* __restrict__ proj_w,
                                                unsigned short* __restrict__ dq,
                                                unsigned short* __restrict__ dc,
                                                unsigned short* __restrict__ dp) {
  int i = blockIdx.x * 256 + threadIdx.x;
  const float* src;
  unsigned short* dst;
  int off;
  if (i < 196608) { src = qkv_w; dst = dq; off = i; }                 // 3*512*512/4
  else if (i < 393216) { src = ckv_w; dst = dc; off = i - 196608; }   // 2*512*768/4
  else { src = proj_w; dst = dp; off = i - 393216; }                  // 512*512/4
  float4 v = *(const float4*)(src + (size_t)off * 4);
  u16x4 o;
  o[0] = f2bf(v.x); o[1] = f2bf(v.y); o[2] = f2bf(v.z); o[3] = f2bf(v.w);
  *(u16x4*)(dst + (size_t)off * 4) = o;
}

__global__ __launch_bounds__(256) void conv_ctx_k(const float* __restrict__ ctx,
                                                  unsigned short* __restrict__ dst) {
  int i = blockIdx.x * 256 + threadIdx.x;
  int total4 = B_ * LP_ * CTX_ / 4;
  if (i >= total4) return;
  int idx = i * 4;
  int b = idx / (LP_ * CTX_);
  int rem = idx - b * (LP_ * CTX_);
  int l = rem / CTX_;
  int c = rem - l * CTX_;
  float4 v = make_float4(0.f, 0.f, 0.f, 0.f);
  if (l < L_) v = *(const float4*)&ctx[((size_t)b * L_ + l) * CTX_ + c];
  u16x4 o;
  o[0] = f2bf(v.x); o[1] = f2bf(v.y); o[2] = f2bf(v.z); o[3] = f2bf(v.w);
  *(u16x4*)(dst + idx) = o;
}

// zero the KV pad rows (1101..1151)
__global__ __launch_bounds__(256) void pad_zero_k(unsigned short* __restrict__ k_s,
                                                  unsigned short* __restrict__ vT) {
  int i = blockIdx.x * 256 + threadIdx.x;
  const int total = 64 * (KVP_ - KV_) * 64;
  if (i >= total) return;
  int bh = i / ((KVP_ - KV_) * 64);
  int rem = i - bh * ((KVP_ - KV_) * 64);
  int row = KV_ + rem / 64;
  int d = rem & 63;
  k_s[((size_t)bh * KVP_ + row) * HD_ + d] = 0;
  vT[((size_t)bh * HD_ + d) * KVP_ + row] = 0;
}

// ---------------- groupnorm (fused stats+normalize+transpose) ----------------
__global__ __launch_bounds__(256) void gnorm_k(const float* __restrict__ x,
                                               const float* __restrict__ gamma,
                                               const float* __restrict__ beta,
                                               unsigned short* __restrict__ xn_t) {
  __shared__ unsigned short xs[16][1032];
  __shared__ float red[8];
  const int tid = threadIdx.x;
  const int b = blockIdx.x >> 5, g = blockIdx.x & 31;
  const float* xp = x + ((size_t)b * DIM_ + g * 16) * HW_;
  float sum = 0.f, ssq = 0.f;
#pragma unroll
  for (int i = 0; i < 16; ++i) {
    float4 v = *(const float4*)&xp[i * HW_ + tid * 4];
    sum += v.x + v.y + v.z + v.w;
    ssq += v.x * v.x + v.y * v.y + v.z * v.z + v.w * v.w;
    xs[i][tid * 4 + 0] = f2bf(v.x);
    xs[i][tid * 4 + 1] = f2bf(v.y);
    xs[i][tid * 4 + 2] = f2bf(v.z);
    xs[i][tid * 4 + 3] = f2bf(v.w);
  }
#pragma unroll
  for (int off = 32; off >= 1; off >>= 1) {
    sum += __shfl_xor(sum, off, 64);
    ssq += __shfl_xor(ssq, off, 64);
  }
  if ((tid & 63) == 0) { red[(tid >> 6) * 2] = sum; red[(tid >> 6) * 2 + 1] = ssq; }
  __syncthreads();
  sum = red[0] + red[2] + red[4] + red[6];
  ssq = red[1] + red[3] + red[5] + red[7];
  float mu = sum * (1.f / 16384.f);
  float rstd = rsqrtf(ssq * (1.f / 16384.f) - mu * mu + 1e-5f);
  float a[16], c[16];
#pragma unroll
  for (int ci = 0; ci < 16; ++ci) {
    float gm = gamma[g * 16 + ci], bt = beta[g * 16 + ci];
    a[ci] = rstd * gm;
    c[ci] = bt - mu * rstd * gm;
  }
#pragma unroll
  for (int t = 0; t < 4; ++t) {
    int hw = tid + t * 256;
    unsigned short tmp[16];
#pragma unroll
    for (int ci = 0; ci < 16; ++ci)
      tmp[ci] = f2bf(bf2f(xs[ci][hw]) * a[ci] + c[ci]);
    unsigned int w[8];
#pragma unroll
    for (int j = 0; j < 8; ++j) w[j] = (unsigned int)tmp[2 * j] | ((unsigned int)tmp[2 * j + 1] << 16);
    unsigned short* dptr = &xn_t[((size_t)b * HW_ + hw) * DIM_ + g * 16];
    *(uint4*)dptr = make_uint4(w[0], w[1], w[2], w[3]);
    *(uint4*)(dptr + 8) = make_uint4(w[4], w[5], w[6], w[7]);
  }
}

// ---------------- GEMM body: C[m][n] = sum_k A[m][k]*Bt[n][k] ----------------
// BM x BN tiles, 2x2 waves, dbuf LDS with COUNTED vmcnt (stage t+1 stays in
// flight across the barrier; vmcnt(0) only on the last K-step), T2 XOR
// chunk-swizzle on stage source + LDS reads.
// MODE 0: qkv -> LDS-transpose epilogue, coalesced q/k/v stores (+bias, SC_QK)
// MODE 1: ckv -> scalar scatter to k_s/vT at rows 1024+l
// MODE 2: proj -> out = acc + bias[row] + x (residual), coalesced f32
template <int MODE, int BM, int BN>
__device__ __forceinline__ void gemm_body(int bid,
                                          const unsigned short* __restrict__ A,
                                          const unsigned short* __restrict__ Bt,
                                          int M, int N, int K,
                                          const float* __restrict__ bias,
                                          unsigned short* __restrict__ out_q,
                                          unsigned short* __restrict__ out_k,
                                          unsigned short* __restrict__ out_v,
                                          const float* __restrict__ xres,
                                          float* __restrict__ outf,
                                          unsigned short* sm) {
  constexpr int MR = BM / 32;
  constexpr int NR = BN / 32;
  constexpr int SLOADS = BM / 32 + BN / 32;  // gload_lds per thread per stage
  unsigned short* As0 = sm;                  // [2][BM*64]
  unsigned short* Bs0 = sm + 2 * BM * 64;    // [2][BN*64]
  const int tid = threadIdx.x;
  const int wid = tid >> 6, lane = tid & 63;
  const int lr = lane & 15, lg = lane >> 4;
  const int ntn = N / BN;
  const int tm = bid / ntn, tn = bid - tm * ntn;
  const int m0 = tm * BM, n0 = tn * BN;
  const int wr = wid >> 1, wc = wid & 1;
  f32x4 acc[MR][NR] = {};
  const int nkt = K >> 6;

  auto stage = [&](int bi, int kk) {
#pragma unroll
    for (int i = 0; i < BM / 32; ++i) {
      int c = i * 256 + tid;
      int row = c >> 3, ch = (c & 7) ^ (row & 7);
      GLD_LDS16(A + (size_t)(m0 + row) * K + kk + ch * 8,
                As0 + (size_t)bi * BM * 64 + (size_t)(i * 256 + wid * 64) * 8);
    }
#pragma unroll
    for (int i = 0; i < BN / 32; ++i) {
      int c = i * 256 + tid;
      int row = c >> 3, ch = (c & 7) ^ (row & 7);
      GLD_LDS16(Bt + (size_t)(n0 + row) * K + kk + ch * 8,
                Bs0 + (size_t)bi * BN * 64 + (size_t)(i * 256 + wid * 64) * 8);
    }
  };

  // prologue: pin issue order so the counted vmcnt is exact
  __builtin_amdgcn_sched_barrier(0);
  stage(0, 0);
  __builtin_amdgcn_sched_barrier(0);
  if (nkt > 1) stage(1, 64);
  __builtin_amdgcn_sched_barrier(0);

  for (int kt = 0; kt < nkt; ++kt) {
    // stage(kt) landed; stage(kt+1) stays in flight across the barrier
    if (kt < nkt - 1) {
      if constexpr (SLOADS == 8)      asm volatile("s_waitcnt vmcnt(8)" ::: "memory");
      else if constexpr (SLOADS == 6) asm volatile("s_waitcnt vmcnt(6)" ::: "memory");
      else                            asm volatile("s_waitcnt vmcnt(0)" ::: "memory");
    } else {
      asm volatile("s_waitcnt vmcnt(0)" ::: "memory");
    }
    __builtin_amdgcn_sched_barrier(0);
    __builtin_amdgcn_s_barrier();
    __builtin_amdgcn_sched_barrier(0);
    const unsigned short* Ab = As0 + (kt & 1) * BM * 64;
    const unsigned short* Bb = Bs0 + (kt & 1) * BN * 64;
#pragma unroll
    for (int ks = 0; ks < 2; ++ks) {
      bf16x8 af[MR], bf[NR];
#pragma unroll
      for (int mi = 0; mi < MR; ++mi)
        af[mi] = *(const bf16x8*)&Ab[(wr * (BM / 2) + mi * 16 + lr) * 64 +
                                     (((ks * 4 + lg) ^ (lr & 7)) * 8)];
#pragma unroll
      for (int nj = 0; nj < NR; ++nj)
        bf[nj] = *(const bf16x8*)&Bb[(wc * (BN / 2) + nj * 16 + lr) * 64 +
                                     (((ks * 4 + lg) ^ (lr & 7)) * 8)];
#pragma unroll
      for (int mi = 0; mi < MR; ++mi)
#pragma unroll
        for (int nj = 0; nj < NR; ++nj)
          acc[mi][nj] = __builtin_amdgcn_mfma_f32_16x16x32_bf16(af[mi], bf[nj], acc[mi][nj], 0, 0, 0);
    }
    asm volatile("s_waitcnt lgkmcnt(0)" ::: "memory");
    __builtin_amdgcn_sched_barrier(0);
    __builtin_amdgcn_s_barrier();
    __builtin_amdgcn_sched_barrier(0);
    if (kt + 2 < nkt) stage(kt & 1, (kt + 2) << 6);
  }

  if constexpr (MODE == 0) {
    const int which = n0 >> 9;         // uniform per block: 0=q 1=k 2=v
    const int bb = m0 >> 10;
    const int qibase = m0 & 1023;
    if (which == 2) {
      // transpose v through LDS: logical [col 128][qi-chunk 32] of uint2 (4 bf16)
      uint2* Vt = (uint2*)sm;
#pragma unroll
      for (int mi = 0; mi < MR; ++mi) {
#pragma unroll
        for (int nj = 0; nj < NR; ++nj) {
          int col = wc * 64 + nj * 16 + lr;
          float b = bias[n0 + col];
          unsigned int w0, w1;
          float v0 = acc[mi][nj][0] + b, v1 = acc[mi][nj][1] + b;
          float v2 = acc[mi][nj][2] + b, v3 = acc[mi][nj][3] + b;
          asm("v_cvt_pk_bf16_f32 %0, %1, %2" : "=v"(w0) : "v"(v0), "v"(v1));
          asm("v_cvt_pk_bf16_f32 %0, %1, %2" : "=v"(w1) : "v"(v2), "v"(v3));
          int chunk = (wr * 16 + mi * 4 + lg) ^ (lr * 2);
          Vt[col * 32 + chunk] = make_uint2(w0, w1);
        }
      }
      __syncthreads();
#pragma unroll
      for (int it = 0; it < 8; ++it) {
        int col = wid * 32 + it * 4 + lg;
        uint4 val = *(uint4*)&Vt[col * 32 + ((lr * 2) ^ ((col & 15) * 2))];
        int colg = n0 + col;
        int head = (colg >> 6) & 7, d = colg & 63;
        *(uint4*)&out_v[(((size_t)bb * HEADS_ + head) * HD_ + d) * KVP_ + qibase + lr * 8] = val;
      }
    } else {
      // q/k: [qi 128][col 128 (+4 pad)] in LDS, then coalesced 16B row stores
      unsigned short* Tq = sm;
#pragma unroll
      for (int mi = 0; mi < MR; ++mi) {
#pragma unroll
        for (int nj = 0; nj < NR; ++nj) {
          int col = wc * 64 + nj * 16 + lr;
          float b = bias[n0 + col];
          int qr = wr * 64 + mi * 16 + lg * 4;
#pragma unroll
          for (int r = 0; r < 4; ++r)
            Tq[(qr + r) * 132 + col] = f2bf((acc[mi][nj][r] + b) * SC_QK);
        }
      }
      __syncthreads();
#pragma unroll
      for (int it = 0; it < 8; ++it) {
        int qi = wid * 32 + it * 4 + lg;
        uint2 lo = *(uint2*)&Tq[qi * 132 + lr * 8];
        uint2 hi = *(uint2*)&Tq[qi * 132 + lr * 8 + 4];
        uint4 val = make_uint4(lo.x, lo.y, hi.x, hi.y);
        int colg = n0 + lr * 8;
        int head = (colg >> 6) & 7, d = colg & 63;
        size_t bh = (size_t)bb * HEADS_ + head;
        if (which == 0)
          *(uint4*)&out_q[(bh * HW_ + qibase + qi) * HD_ + d] = val;
        else
          *(uint4*)&out_k[(bh * KVP_ + qibase + qi) * HD_ + d] = val;
      }
    }
  } else {
#pragma unroll
    for (int mi = 0; mi < MR; ++mi) {
#pragma unroll
      for (int nj = 0; nj < NR; ++nj) {
#pragma unroll
        for (int r = 0; r < 4; ++r) {
          int row = m0 + wr * (BM / 2) + mi * 16 + lg * 4 + r;
          int col = n0 + wc * (BN / 2) + nj * 16 + lr;
          float v = acc[mi][nj][r];
          if (MODE == 1) {
            int bb = row / LP_, l = row - bb * LP_;
            if (l < L_) {
              v += bias[col];
              int which = col >> 9, head = (col >> 6) & 7, d = col & 63;
              size_t bh = (size_t)bb * HEADS_ + head;
              if (which == 0) out_k[(bh * KVP_ + CTX0_ + l) * HD_ + d] = f2bf(v * SC_QK);
              else            out_v[(bh * HD_ + d) * KVP_ + CTX0_ + l] = f2bf(v);
            }
          } else {
            size_t idx = (size_t)(col >> 10) * (DIM_ * HW_) + (size_t)row * HW_ + (col & 1023);
            outf[idx] = v + bias[row] + xres[idx];
          }
        }
      }
    }
  }
}

// fused qkv (blocks 0..767, XCD-swizzled) + ckv (blocks 768..807) — the 40
// latency-bound ckv blocks hide under the 768 qkv blocks.
__global__ __launch_bounds__(256, 2) void gemm_qkv_ckv_k(
    const unsigned short* __restrict__ xn_t, const unsigned short* __restrict__ qkvw,
    const unsigned short* __restrict__ ctx_bf, const unsigned short* __restrict__ ckvw,
    const float* __restrict__ qkv_b, const float* __restrict__ ckv_b,
    unsigned short* __restrict__ q_s, unsigned short* __restrict__ k_s,
    unsigned short* __restrict__ vT) {
  __shared__ unsigned short sm[2 * 256 * 64];
  int bid = blockIdx.x;
  if (bid < 768) {
    int b2 = (bid & 7) * 96 + (bid >> 3);
    gemm_body<0, 128, 128>(b2, xn_t, qkvw, 8192, 1536, 512, qkv_b,
                           q_s, k_s, vT, nullptr, nullptr, sm);
  } else {
    gemm_body<1, 128, 128>(bid - 768, ctx_bf, ckvw, 640, 1024, 768, ckv_b,
                           nullptr, k_s, vT, nullptr, nullptr, sm);
  }
}

__global__ __launch_bounds__(256, 2) void gemm_proj_k(
    const unsigned short* __restrict__ projw, const unsigned short* __restrict__ at_s,
    const float* __restrict__ proj_b, const float* __restrict__ x,
    float* __restrict__ out) {
  __shared__ unsigned short sm[2 * 192 * 64];
  gemm_body<2, 64, 128>(blockIdx.x, projw, at_s, 512, 8192, 512, proj_b,
                        nullptr, nullptr, nullptr, x, out, sm);
}

// ---------------- flash attention: 8-wave blocks, 1 q-col/wave, no-max softmax ----------------
// Scores are bounded: q,k pre-scaled by SC_QK (|S_log2| << 126), so softmax uses
// p = exp2(S) directly (exact after final /sum) — no online max, no rescale.
#define PSTRIDE 72

template <bool MASK>
__device__ __forceinline__ void attn_tile64(const unsigned short* __restrict__ Ksb,
                                            const unsigned short* __restrict__ Vsb,
                                            int krem,
                                            const bf16x8 (&qf)[2],
                                            unsigned short* __restrict__ Pw,
                                            int lr, int lg,
                                            const int (&ro)[4], const int (&koff)[2],
                                            float& lrun, f32x4 (&acc)[4]) {
  f32x4 st[4] = {};
  __builtin_amdgcn_s_setprio(1);
#pragma unroll
  for (int ks = 0; ks < 2; ++ks) {
    bf16x8 kf[4];
#pragma unroll
    for (int t = 0; t < 4; ++t)
      kf[t] = *(const bf16x8*)&Ksb[ro[t] + koff[ks]];
#pragma unroll
    for (int t = 0; t < 4; ++t)
      st[t] = __builtin_amdgcn_mfma_f32_16x16x32_bf16(kf[t], qf[ks], st[t], 0, 0, 0);
  }
  __builtin_amdgcn_s_setprio(0);
  if (MASK) {
#pragma unroll
    for (int t = 0; t < 4; ++t)
#pragma unroll
      for (int r = 0; r < 4; ++r)
        st[t][r] = (t * 16 + lg * 4 + r < krem) ? st[t][r] : -INFINITY;
  }
  // p = exp2(S), no max subtraction
#pragma unroll
  for (int t = 0; t < 4; ++t)
#pragma unroll
    for (int r = 0; r < 4; ++r) st[t][r] = exp2f(st[t][r]);
  float s0 = (st[0][0] + st[0][1]) + (st[0][2] + st[0][3]);
  float s1 = (st[1][0] + st[1][1]) + (st[1][2] + st[1][3]);
  float s2 = (st[2][0] + st[2][1]) + (st[2][2] + st[2][3]);
  float s3 = (st[3][0] + st[3][1]) + (st[3][2] + st[3][3]);
  float rs = (s0 + s1) + (s2 + s3);
  rs += __shfl_xor(rs, 16, 64);
  rs += __shfl_xor(rs, 32, 64);
  lrun += rs;
  // pack P^T -> [q=lr][k] LDS
#pragma unroll
  for (int t = 0; t < 4; ++t) {
    unsigned int w0, w1;
    asm("v_cvt_pk_bf16_f32 %0, %1, %2" : "=v"(w0) : "v"(st[t][0]), "v"(st[t][1]));
    asm("v_cvt_pk_bf16_f32 %0, %1, %2" : "=v"(w1) : "v"(st[t][2]), "v"(st[t][3]));
    *(uint2*)&Pw[lr * PSTRIDE + t * 16 + lg * 4] = make_uint2(w0, w1);
  }
  // PV: O^T[d][q] += V^T[d][k] · P[q][k]
#pragma unroll
  for (int ks = 0; ks < 2; ++ks) {
    bf16x8 pb = *(const bf16x8*)&Pw[lr * PSTRIDE + ks * 32 + lg * 8];
    __builtin_amdgcn_s_setprio(1);
#pragma unroll
    for (int dt = 0; dt < 4; ++dt) {
      bf16x8 vf = *(const bf16x8*)&Vsb[ro[dt] + koff[ks]];
      acc[dt] = __builtin_amdgcn_mfma_f32_16x16x32_bf16(vf, pb, acc[dt], 0, 0, 0);
    }
    __builtin_amdgcn_s_setprio(0);
  }
}

__global__ __launch_bounds__(512, 4) void attn_k(const unsigned short* __restrict__ q_s,
                                                 const unsigned short* __restrict__ k_s,
                                                 const unsigned short* __restrict__ vT,
                                                 unsigned short* __restrict__ at_s) {
  __shared__ unsigned short Ks[2][4096];
  __shared__ unsigned short Vs[2][4096];
  __shared__ unsigned short Pb[8][16 * PSTRIDE];
  const int tid = threadIdx.x;
  const int wid = tid >> 6, lane = tid & 63;
  const int lr = lane & 15, lg = lane >> 4;
  // grid = 512: 64 bh x 8 qtiles of 128 q; XCD-bijective swizzle
  const int bidx = blockIdx.x;
  const int xcd = bidx & 7, idx = bidx >> 3;
  const int bh = xcd + 8 * (idx >> 3);
  const int qt = idx & 7;
  const int q0 = qt * 128 + wid * 16;   // one 16-q col per wave
  const unsigned short* qp = q_s + (size_t)bh * HW_ * HD_;
  const unsigned short* kp = k_s + (size_t)bh * KVP_ * HD_;
  const unsigned short* vp = vT + (size_t)bh * HD_ * KVP_;
  unsigned short* Pw = Pb[wid];

  const int srow = lane >> 3;
  const int schunk = (lane & 7) ^ srow;

  // one stage = exactly 2 gload_lds per wave (waves 0-3: K, waves 4-7: V)
  auto stage = [&](int bufi, int kk) {
    if (wid < 4) {
#pragma unroll
      for (int jj = 0; jj < 2; ++jj)
        GLD_LDS16(kp + (size_t)(kk + wid * 16 + jj * 8 + srow) * HD_ + schunk * 8,
                  &Ks[bufi][(wid * 2 + jj) * 512]);
    } else {
#pragma unroll
      for (int jj = 0; jj < 2; ++jj)
        GLD_LDS16(vp + (size_t)((wid - 4) * 16 + jj * 8 + srow) * KVP_ + kk + schunk * 8,
                  &Vs[bufi][((wid - 4) * 2 + jj) * 512]);
    }
  };

  int ro[4], koff[2];
#pragma unroll
  for (int t = 0; t < 4; ++t) ro[t] = (t * 16 + lr) * 64;
#pragma unroll
  for (int ks = 0; ks < 2; ++ks) koff[ks] = ((ks * 4 + lg) ^ (lr & 7)) * 8;

  bf16x8 qf[2];
#pragma unroll
  for (int ks = 0; ks < 2; ++ks)
    qf[ks] = *(const bf16x8*)&qp[(size_t)(q0 + lr) * HD_ + ks * 32 + lg * 8];

  f32x4 acc[4] = {};
  float lrun = 0.f;

  // prologue: pin issue order so counted vmcnt at loop head is exact
  __builtin_amdgcn_sched_barrier(0);
  stage(0, 0);
  __builtin_amdgcn_sched_barrier(0);
  stage(1, 64);
  __builtin_amdgcn_sched_barrier(0);

  int cur = 0;
  for (int it = 0; it < 17; ++it) {
    // my stage(it) loads landed; stage(it+1) stays in flight across the barrier
    asm volatile("s_waitcnt vmcnt(2)" ::: "memory");
    __builtin_amdgcn_sched_barrier(0);
    __builtin_amdgcn_s_barrier();
    __builtin_amdgcn_sched_barrier(0);
    attn_tile64<false>(Ks[cur], Vs[cur], 64, qf, Pw, lr, lg, ro, koff, lrun, acc);
    asm volatile("s_waitcnt lgkmcnt(0)" ::: "memory");
    __builtin_amdgcn_sched_barrier(0);
    __builtin_amdgcn_s_barrier();
    __builtin_amdgcn_sched_barrier(0);
    if (it < 16) stage(cur, (it + 2) * 64);
    cur ^= 1;
  }
  // final tile: full drain, masked at KV_
  asm volatile("s_waitcnt vmcnt(0)" ::: "memory");
  __builtin_amdgcn_sched_barrier(0);
  __builtin_amdgcn_s_barrier();
  __builtin_amdgcn_sched_barrier(0);
  attn_tile64<true>(Ks[cur], Vs[cur], KV_ - 17 * 64, qf, Pw, lr, lg, ro, koff, lrun, acc);

  const int bb = bh >> 3, head = bh & 7;
  const float inv = 1.f / lrun;
  const int qi = q0 + lr;
#pragma unroll
  for (int dt = 0; dt < 4; ++dt) {
    u16x4 o;
#pragma unroll
    for (int r = 0; r < 4; ++r) o[r] = f2bf(acc[dt][r] * inv);
    *(u16x4*)&at_s[((size_t)bb * HW_ + qi) * DIM_ + head * HD_ + dt * 16 + lg * 4] = o;
  }
}

extern "C" void kernel_launch(void* const* d_in, const int* in_sizes, int n_in,
                              void* d_out, int out_size, void* d_ws, size_t ws_size,
                              hipStream_t stream) {
  (void)in_sizes; (void)n_in; (void)out_size; (void)ws_size;
  const float* x      = (const float*)d_in[0];
  const float* ctx    = (const float*)d_in[1];
  const float* gng    = (const float*)d_in[2];
  const float* gnb    = (const float*)d_in[3];
  const float* qkv_w  = (const float*)d_in[4];
  const float* qkv_b  = (const float*)d_in[5];
  const float* ckv_w  = (const float*)d_in[6];
  const float* ckv_b  = (const float*)d_in[7];
  const float* proj_w = (const float*)d_in[8];
  const float* proj_b = (const float*)d_in[9];
  float* out = (float*)d_out;

  char* ws = (char*)d_ws;
  size_t off = 0;
  auto alloc = [&](size_t bytes) {
    char* p = ws + off;
    off = (off + bytes + 255) & ~(size_t)255;
    return p;
  };
  unsigned short* xn_t    = (unsigned short*)alloc((size_t)B_ * HW_ * DIM_ * 2);
  unsigned short* ctx_bf  = (unsigned short*)alloc((size_t)B_ * LP_ * CTX_ * 2);
  unsigned short* qkvw_bf = (unsigned short*)alloc((size_t)3 * DIM_ * DIM_ * 2);
  unsigned short* ckvw_bf = (unsigned short*)alloc((size_t)2 * DIM_ * CTX_ * 2);
  unsigned short* projw_bf= (unsigned short*)alloc((size_t)DIM_ * DIM_ * 2);
  unsigned short* q_s     = (unsigned short*)alloc((size_t)64 * HW_ * HD_ * 2);
  unsigned short* k_s     = (unsigned short*)alloc((size_t)64 * KVP_ * HD_ * 2);
  unsigned short* vT      = (unsigned short*)alloc((size_t)64 * HD_ * KVP_ * 2);
  unsigned short* at_s    = (unsigned short*)alloc((size_t)B_ * HW_ * DIM_ * 2);

  conv_w_k<<<1792, 256, 0, stream>>>(qkv_w, ckv_w, proj_w, qkvw_bf, ckvw_bf, projw_bf);
  conv_ctx_k<<<480, 256, 0, stream>>>(ctx, ctx_bf);
  gnorm_k<<<256, 256, 0, stream>>>(x, gng, gnb, xn_t);
  pad_zero_k<<<816, 256, 0, stream>>>(k_s, vT);
  gemm_qkv_ckv_k<<<808, 256, 0, stream>>>(xn_t, qkvw_bf, ctx_bf, ckvw_bf,
                                          qkv_b, ckv_b, q_s, k_s, vT);
  attn_k<<<512, 512, 0, stream>>>(q_s, k_s, vT, at_s);
  gemm_proj_k<<<512, 256, 0, stream>>>(projw_bf, at_s, proj_b, x, out);
}

// Round 10
// 88.359 us; speedup vs baseline: 1.4631x; 1.1833x over previous
//
#include <hip/hip_runtime.h>

#define B_ 8
#define DIM_ 512
#define HEADS_ 8
#define HD_ 64
#define HW_ 1024
#define L_ 77
#define LP_ 80
#define CTX_ 768
#define KV_ 1101
#define KVP_ 1152
// internal KV order: self-attn rows [0,1024), context rows [1024,1101), pad [1101,1152)
#define CTX0_ 1024
// sqrt(SCALE^2 * log2(e)) folded into both q and k: 64^-0.25 * sqrt(1.4426950409)
#define SC_QK 0.42466089f

typedef __attribute__((ext_vector_type(8))) short bf16x8;
typedef __attribute__((ext_vector_type(4))) float f32x4;
typedef __attribute__((ext_vector_type(4))) unsigned short u16x4;

__device__ __forceinline__ unsigned short f2bf(float f) {
  union { float f; unsigned int u; } c; c.f = f;
  unsigned int u = c.u;
  return (unsigned short)((u + 0x7fffu + ((u >> 16) & 1u)) >> 16);
}
__device__ __forceinline__ float bf2f(unsigned short h) {
  union { unsigned int u; float f; } c; c.u = ((unsigned int)h) << 16;
  return c.f;
}

#define GLD_LDS16(gsrc, ldst) \
  __builtin_amdgcn_global_load_lds((const __attribute__((address_space(1))) void*)(gsrc), \
                                   (__attribute__((address_space(3))) void*)(ldst), 16, 0, 0)

// ---------------- converts ----------------
// merged f32->bf16 convert of the three weight matrices (one launch)
__global__ __launch_bounds__(256) void conv_w_k(const float* __restrict__ qkv_w,
                                                const float* __restrict__ ckv_w,
                                                const float* __restrict__ proj_w,
                                                unsigned short* __restrict__ dq,
                                                unsigned short* __restrict__ dc,
                                                unsigned short* __restrict__ dp) {
  int i = blockIdx.x * 256 + threadIdx.x;
  const float* src;
  unsigned short* dst;
  int off;
  if (i < 196608) { src = qkv_w; dst = dq; off = i; }                 // 3*512*512/4
  else if (i < 393216) { src = ckv_w; dst = dc; off = i - 196608; }   // 2*512*768/4
  else { src = proj_w; dst = dp; off = i - 393216; }                  // 512*512/4
  float4 v = *(const float4*)(src + (size_t)off * 4);
  u16x4 o;
  o[0] = f2bf(v.x); o[1] = f2bf(v.y); o[2] = f2bf(v.z); o[3] = f2bf(v.w);
  *(u16x4*)(dst + (size_t)off * 4) = o;
}

__global__ __launch_bounds__(256) void conv_ctx_k(const float* __restrict__ ctx,
                                                  unsigned short* __restrict__ dst) {
  int i = blockIdx.x * 256 + threadIdx.x;
  int total4 = B_ * LP_ * CTX_ / 4;
  if (i >= total4) return;
  int idx = i * 4;
  int b = idx / (LP_ * CTX_);
  int rem = idx - b * (LP_ * CTX_);
  int l = rem / CTX_;
  int c = rem - l * CTX_;
  float4 v = make_float4(0.f, 0.f, 0.f, 0.f);
  if (l < L_) v = *(const float4*)&ctx[((size_t)b * L_ + l) * CTX_ + c];
  u16x4 o;
  o[0] = f2bf(v.x); o[1] = f2bf(v.y); o[2] = f2bf(v.z); o[3] = f2bf(v.w);
  *(u16x4*)(dst + idx) = o;
}

// zero the KV pad rows (1101..1151)
__global__ __launch_bounds__(256) void pad_zero_k(unsigned short* __restrict__ k_s,
                                                  unsigned short* __restrict__ vT) {
  int i = blockIdx.x * 256 + threadIdx.x;
  const int total = 64 * (KVP_ - KV_) * 64;
  if (i >= total) return;
  int bh = i / ((KVP_ - KV_) * 64);
  int rem = i - bh * ((KVP_ - KV_) * 64);
  int row = KV_ + rem / 64;
  int d = rem & 63;
  k_s[((size_t)bh * KVP_ + row) * HD_ + d] = 0;
  vT[((size_t)bh * HD_ + d) * KVP_ + row] = 0;
}

// ---------------- groupnorm (fused stats+normalize+transpose) ----------------
__global__ __launch_bounds__(256) void gnorm_k(const float* __restrict__ x,
                                               const float* __restrict__ gamma,
                                               const float* __restrict__ beta,
                                               unsigned short* __restrict__ xn_t) {
  __shared__ unsigned short xs[16][1032];
  __shared__ float red[8];
  const int tid = threadIdx.x;
  const int b = blockIdx.x >> 5, g = blockIdx.x & 31;
  const float* xp = x + ((size_t)b * DIM_ + g * 16) * HW_;
  float sum = 0.f, ssq = 0.f;
#pragma unroll
  for (int i = 0; i < 16; ++i) {
    float4 v = *(const float4*)&xp[i * HW_ + tid * 4];
    sum += v.x + v.y + v.z + v.w;
    ssq += v.x * v.x + v.y * v.y + v.z * v.z + v.w * v.w;
    xs[i][tid * 4 + 0] = f2bf(v.x);
    xs[i][tid * 4 + 1] = f2bf(v.y);
    xs[i][tid * 4 + 2] = f2bf(v.z);
    xs[i][tid * 4 + 3] = f2bf(v.w);
  }
#pragma unroll
  for (int off = 32; off >= 1; off >>= 1) {
    sum += __shfl_xor(sum, off, 64);
    ssq += __shfl_xor(ssq, off, 64);
  }
  if ((tid & 63) == 0) { red[(tid >> 6) * 2] = sum; red[(tid >> 6) * 2 + 1] = ssq; }
  __syncthreads();
  sum = red[0] + red[2] + red[4] + red[6];
  ssq = red[1] + red[3] + red[5] + red[7];
  float mu = sum * (1.f / 16384.f);
  float rstd = rsqrtf(ssq * (1.f / 16384.f) - mu * mu + 1e-5f);
  float a[16], c[16];
#pragma unroll
  for (int ci = 0; ci < 16; ++ci) {
    float gm = gamma[g * 16 + ci], bt = beta[g * 16 + ci];
    a[ci] = rstd * gm;
    c[ci] = bt - mu * rstd * gm;
  }
#pragma unroll
  for (int t = 0; t < 4; ++t) {
    int hw = tid + t * 256;
    unsigned short tmp[16];
#pragma unroll
    for (int ci = 0; ci < 16; ++ci)
      tmp[ci] = f2bf(bf2f(xs[ci][hw]) * a[ci] + c[ci]);
    unsigned int w[8];
#pragma unroll
    for (int j = 0; j < 8; ++j) w[j] = (unsigned int)tmp[2 * j] | ((unsigned int)tmp[2 * j + 1] << 16);
    unsigned short* dptr = &xn_t[((size_t)b * HW_ + hw) * DIM_ + g * 16];
    *(uint4*)dptr = make_uint4(w[0], w[1], w[2], w[3]);
    *(uint4*)(dptr + 8) = make_uint4(w[4], w[5], w[6], w[7]);
  }
}

// ---------------- GEMM body: C[m][n] = sum_k A[m][k]*Bt[n][k] ----------------
// BM x BN tiles, 2x2 waves, dbuf LDS with COUNTED vmcnt (stage t+1 stays in
// flight across the barrier; vmcnt(0) only on the last K-step), T2 XOR
// chunk-swizzle on stage source + LDS reads.
// MODE 0: qkv -> LDS-transpose epilogue, coalesced q/k/v stores (+bias, SC_QK)
// MODE 1: ckv -> scalar scatter to k_s/vT at rows 1024+l
// MODE 2: proj -> out = acc + bias[row] + x (residual), coalesced f32
template <int MODE, int BM, int BN>
__device__ __forceinline__ void gemm_body(int bid,
                                          const unsigned short* __restrict__ A,
                                          const unsigned short* __restrict__ Bt,
                                          int M, int N, int K,
                                          const float* __restrict__ bias,
                                          unsigned short* __restrict__ out_q,
                                          unsigned short* __restrict__ out_k,
                                          unsigned short* __restrict__ out_v,
                                          const float* __restrict__ xres,
                                          float* __restrict__ outf,
                                          unsigned short* sm) {
  constexpr int MR = BM / 32;
  constexpr int NR = BN / 32;
  constexpr int SLOADS = BM / 32 + BN / 32;  // gload_lds per thread per stage
  unsigned short* As0 = sm;                  // [2][BM*64]
  unsigned short* Bs0 = sm + 2 * BM * 64;    // [2][BN*64]
  const int tid = threadIdx.x;
  const int wid = tid >> 6, lane = tid & 63;
  const int lr = lane & 15, lg = lane >> 4;
  const int ntn = N / BN;
  const int tm = bid / ntn, tn = bid - tm * ntn;
  const int m0 = tm * BM, n0 = tn * BN;
  const int wr = wid >> 1, wc = wid & 1;
  f32x4 acc[MR][NR] = {};
  const int nkt = K >> 6;

  auto stage = [&](int bi, int kk) {
#pragma unroll
    for (int i = 0; i < BM / 32; ++i) {
      int c = i * 256 + tid;
      int row = c >> 3, ch = (c & 7) ^ (row & 7);
      GLD_LDS16(A + (size_t)(m0 + row) * K + kk + ch * 8,
                As0 + (size_t)bi * BM * 64 + (size_t)(i * 256 + wid * 64) * 8);
    }
#pragma unroll
    for (int i = 0; i < BN / 32; ++i) {
      int c = i * 256 + tid;
      int row = c >> 3, ch = (c & 7) ^ (row & 7);
      GLD_LDS16(Bt + (size_t)(n0 + row) * K + kk + ch * 8,
                Bs0 + (size_t)bi * BN * 64 + (size_t)(i * 256 + wid * 64) * 8);
    }
  };

  // prologue: pin issue order so the counted vmcnt is exact
  __builtin_amdgcn_sched_barrier(0);
  stage(0, 0);
  __builtin_amdgcn_sched_barrier(0);
  if (nkt > 1) stage(1, 64);
  __builtin_amdgcn_sched_barrier(0);

  for (int kt = 0; kt < nkt; ++kt) {
    // stage(kt) landed; stage(kt+1) stays in flight across the barrier
    if (kt < nkt - 1) {
      if constexpr (SLOADS == 8)      asm volatile("s_waitcnt vmcnt(8)" ::: "memory");
      else if constexpr (SLOADS == 6) asm volatile("s_waitcnt vmcnt(6)" ::: "memory");
      else                            asm volatile("s_waitcnt vmcnt(0)" ::: "memory");
    } else {
      asm volatile("s_waitcnt vmcnt(0)" ::: "memory");
    }
    __builtin_amdgcn_sched_barrier(0);
    __builtin_amdgcn_s_barrier();
    __builtin_amdgcn_sched_barrier(0);
    const unsigned short* Ab = As0 + (kt & 1) * BM * 64;
    const unsigned short* Bb = Bs0 + (kt & 1) * BN * 64;
#pragma unroll
    for (int ks = 0; ks < 2; ++ks) {
      bf16x8 af[MR], bf[NR];
#pragma unroll
      for (int mi = 0; mi < MR; ++mi)
        af[mi] = *(const bf16x8*)&Ab[(wr * (BM / 2) + mi * 16 + lr) * 64 +
                                     (((ks * 4 + lg) ^ (lr & 7)) * 8)];
#pragma unroll
      for (int nj = 0; nj < NR; ++nj)
        bf[nj] = *(const bf16x8*)&Bb[(wc * (BN / 2) + nj * 16 + lr) * 64 +
                                     (((ks * 4 + lg) ^ (lr & 7)) * 8)];
#pragma unroll
      for (int mi = 0; mi < MR; ++mi)
#pragma unroll
        for (int nj = 0; nj < NR; ++nj)
          acc[mi][nj] = __builtin_amdgcn_mfma_f32_16x16x32_bf16(af[mi], bf[nj], acc[mi][nj], 0, 0, 0);
    }
    asm volatile("s_waitcnt lgkmcnt(0)" ::: "memory");
    __builtin_amdgcn_sched_barrier(0);
    __builtin_amdgcn_s_barrier();
    __builtin_amdgcn_sched_barrier(0);
    if (kt + 2 < nkt) stage(kt & 1, (kt + 2) << 6);
  }

  if constexpr (MODE == 0) {
    const int which = n0 >> 9;         // uniform per block: 0=q 1=k 2=v
    const int bb = m0 >> 10;
    const int qibase = m0 & 1023;
    if (which == 2) {
      // transpose v through LDS: logical [col 128][qi-chunk 32] of uint2 (4 bf16)
      uint2* Vt = (uint2*)sm;
#pragma unroll
      for (int mi = 0; mi < MR; ++mi) {
#pragma unroll
        for (int nj = 0; nj < NR; ++nj) {
          int col = wc * 64 + nj * 16 + lr;
          float b = bias[n0 + col];
          unsigned int w0, w1;
          float v0 = acc[mi][nj][0] + b, v1 = acc[mi][nj][1] + b;
          float v2 = acc[mi][nj][2] + b, v3 = acc[mi][nj][3] + b;
          asm("v_cvt_pk_bf16_f32 %0, %1, %2" : "=v"(w0) : "v"(v0), "v"(v1));
          asm("v_cvt_pk_bf16_f32 %0, %1, %2" : "=v"(w1) : "v"(v2), "v"(v3));
          int chunk = (wr * 16 + mi * 4 + lg) ^ (lr * 2);
          Vt[col * 32 + chunk] = make_uint2(w0, w1);
        }
      }
      __syncthreads();
#pragma unroll
      for (int it = 0; it < 8; ++it) {
        int col = wid * 32 + it * 4 + lg;
        uint4 val = *(uint4*)&Vt[col * 32 + ((lr * 2) ^ ((col & 15) * 2))];
        int colg = n0 + col;
        int head = (colg >> 6) & 7, d = colg & 63;
        *(uint4*)&out_v[(((size_t)bb * HEADS_ + head) * HD_ + d) * KVP_ + qibase + lr * 8] = val;
      }
    } else {
      // q/k: [qi 128][col 128 (+4 pad)] in LDS, then coalesced 16B row stores
      unsigned short* Tq = sm;
#pragma unroll
      for (int mi = 0; mi < MR; ++mi) {
#pragma unroll
        for (int nj = 0; nj < NR; ++nj) {
          int col = wc * 64 + nj * 16 + lr;
          float b = bias[n0 + col];
          int qr = wr * 64 + mi * 16 + lg * 4;
#pragma unroll
          for (int r = 0; r < 4; ++r)
            Tq[(qr + r) * 132 + col] = f2bf((acc[mi][nj][r] + b) * SC_QK);
        }
      }
      __syncthreads();
#pragma unroll
      for (int it = 0; it < 8; ++it) {
        int qi = wid * 32 + it * 4 + lg;
        uint2 lo = *(uint2*)&Tq[qi * 132 + lr * 8];
        uint2 hi = *(uint2*)&Tq[qi * 132 + lr * 8 + 4];
        uint4 val = make_uint4(lo.x, lo.y, hi.x, hi.y);
        int colg = n0 + lr * 8;
        int head = (colg >> 6) & 7, d = colg & 63;
        size_t bh = (size_t)bb * HEADS_ + head;
        if (which == 0)
          *(uint4*)&out_q[(bh * HW_ + qibase + qi) * HD_ + d] = val;
        else
          *(uint4*)&out_k[(bh * KVP_ + qibase + qi) * HD_ + d] = val;
      }
    }
  } else {
#pragma unroll
    for (int mi = 0; mi < MR; ++mi) {
#pragma unroll
      for (int nj = 0; nj < NR; ++nj) {
#pragma unroll
        for (int r = 0; r < 4; ++r) {
          int row = m0 + wr * (BM / 2) + mi * 16 + lg * 4 + r;
          int col = n0 + wc * (BN / 2) + nj * 16 + lr;
          float v = acc[mi][nj][r];
          if (MODE == 1) {
            int bb = row / LP_, l = row - bb * LP_;
            if (l < L_) {
              v += bias[col];
              int which = col >> 9, head = (col >> 6) & 7, d = col & 63;
              size_t bh = (size_t)bb * HEADS_ + head;
              if (which == 0) out_k[(bh * KVP_ + CTX0_ + l) * HD_ + d] = f2bf(v * SC_QK);
              else            out_v[(bh * HD_ + d) * KVP_ + CTX0_ + l] = f2bf(v);
            }
          } else {
            size_t idx = (size_t)(col >> 10) * (DIM_ * HW_) + (size_t)row * HW_ + (col & 1023);
            outf[idx] = v + bias[row] + xres[idx];
          }
        }
      }
    }
  }
}

// fused ckv (blocks 0..79, 64x128 tiles — dispatched FIRST so their
// latency-bound chains hide under qkv) + qkv (blocks 80..847, XCD-swizzled).
__global__ __launch_bounds__(256, 2) void gemm_qkv_ckv_k(
    const unsigned short* __restrict__ xn_t, const unsigned short* __restrict__ qkvw,
    const unsigned short* __restrict__ ctx_bf, const unsigned short* __restrict__ ckvw,
    const float* __restrict__ qkv_b, const float* __restrict__ ckv_b,
    unsigned short* __restrict__ q_s, unsigned short* __restrict__ k_s,
    unsigned short* __restrict__ vT) {
  __shared__ unsigned short sm[2 * 256 * 64];
  int bid = blockIdx.x;
  if (bid < 80) {
    gemm_body<1, 64, 128>(bid, ctx_bf, ckvw, 640, 1024, 768, ckv_b,
                          nullptr, k_s, vT, nullptr, nullptr, sm);
  } else {
    int b = bid - 80;
    int b2 = (b & 7) * 96 + (b >> 3);
    gemm_body<0, 128, 128>(b2, xn_t, qkvw, 8192, 1536, 512, qkv_b,
                           q_s, k_s, vT, nullptr, nullptr, sm);
  }
}

__global__ __launch_bounds__(256, 2) void gemm_proj_k(
    const unsigned short* __restrict__ projw, const unsigned short* __restrict__ at_s,
    const float* __restrict__ proj_b, const float* __restrict__ x,
    float* __restrict__ out) {
  __shared__ unsigned short sm[2 * 192 * 64];
  gemm_body<2, 64, 128>(blockIdx.x, projw, at_s, 512, 8192, 512, proj_b,
                        nullptr, nullptr, nullptr, x, out, sm);
}

// ---------------- flash attention: 8-wave blocks, 1 q-col/wave, no-max softmax ----------------
// Scores are bounded: q,k pre-scaled by SC_QK (|S_log2| << 126), so softmax uses
// p = exp2(S) directly (exact after final /sum) — no online max, no rescale.
#define PSTRIDE 72

template <bool MASK>
__device__ __forceinline__ void attn_tile64(const unsigned short* __restrict__ Ksb,
                                            const unsigned short* __restrict__ Vsb,
                                            int krem,
                                            const bf16x8 (&qf)[2],
                                            unsigned short* __restrict__ Pw,
                                            int lr, int lg,
                                            const int (&ro)[4], const int (&koff)[2],
                                            float& lrun, f32x4 (&acc)[4]) {
  f32x4 st[4] = {};
  __builtin_amdgcn_s_setprio(1);
#pragma unroll
  for (int ks = 0; ks < 2; ++ks) {
    bf16x8 kf[4];
#pragma unroll
    for (int t = 0; t < 4; ++t)
      kf[t] = *(const bf16x8*)&Ksb[ro[t] + koff[ks]];
#pragma unroll
    for (int t = 0; t < 4; ++t)
      st[t] = __builtin_amdgcn_mfma_f32_16x16x32_bf16(kf[t], qf[ks], st[t], 0, 0, 0);
  }
  __builtin_amdgcn_s_setprio(0);
  if (MASK) {
#pragma unroll
    for (int t = 0; t < 4; ++t)
#pragma unroll
      for (int r = 0; r < 4; ++r)
        st[t][r] = (t * 16 + lg * 4 + r < krem) ? st[t][r] : -INFINITY;
  }
  // p = exp2(S), no max subtraction
#pragma unroll
  for (int t = 0; t < 4; ++t)
#pragma unroll
    for (int r = 0; r < 4; ++r) st[t][r] = exp2f(st[t][r]);
  float s0 = (st[0][0] + st[0][1]) + (st[0][2] + st[0][3]);
  float s1 = (st[1][0] + st[1][1]) + (st[1][2] + st[1][3]);
  float s2 = (st[2][0] + st[2][1]) + (st[2][2] + st[2][3]);
  float s3 = (st[3][0] + st[3][1]) + (st[3][2] + st[3][3]);
  float rs = (s0 + s1) + (s2 + s3);
  rs += __shfl_xor(rs, 16, 64);
  rs += __shfl_xor(rs, 32, 64);
  lrun += rs;
  // pack P^T -> [q=lr][k] LDS
#pragma unroll
  for (int t = 0; t < 4; ++t) {
    unsigned int w0, w1;
    asm("v_cvt_pk_bf16_f32 %0, %1, %2" : "=v"(w0) : "v"(st[t][0]), "v"(st[t][1]));
    asm("v_cvt_pk_bf16_f32 %0, %1, %2" : "=v"(w1) : "v"(st[t][2]), "v"(st[t][3]));
    *(uint2*)&Pw[lr * PSTRIDE + t * 16 + lg * 4] = make_uint2(w0, w1);
  }
  // PV: O^T[d][q] += V^T[d][k] · P[q][k]
#pragma unroll
  for (int ks = 0; ks < 2; ++ks) {
    bf16x8 pb = *(const bf16x8*)&Pw[lr * PSTRIDE + ks * 32 + lg * 8];
    __builtin_amdgcn_s_setprio(1);
#pragma unroll
    for (int dt = 0; dt < 4; ++dt) {
      bf16x8 vf = *(const bf16x8*)&Vsb[ro[dt] + koff[ks]];
      acc[dt] = __builtin_amdgcn_mfma_f32_16x16x32_bf16(vf, pb, acc[dt], 0, 0, 0);
    }
    __builtin_amdgcn_s_setprio(0);
  }
}

__global__ __launch_bounds__(512, 4) void attn_k(const unsigned short* __restrict__ q_s,
                                                 const unsigned short* __restrict__ k_s,
                                                 const unsigned short* __restrict__ vT,
                                                 unsigned short* __restrict__ at_s) {
  __shared__ unsigned short Ks[2][4096];
  __shared__ unsigned short Vs[2][4096];
  __shared__ unsigned short Pb[8][16 * PSTRIDE];
  const int tid = threadIdx.x;
  const int wid = tid >> 6, lane = tid & 63;
  const int lr = lane & 15, lg = lane >> 4;
  // grid = 512: 64 bh x 8 qtiles of 128 q; XCD-bijective swizzle
  const int bidx = blockIdx.x;
  const int xcd = bidx & 7, idx = bidx >> 3;
  const int bh = xcd + 8 * (idx >> 3);
  const int qt = idx & 7;
  const int q0 = qt * 128 + wid * 16;   // one 16-q col per wave
  const unsigned short* qp = q_s + (size_t)bh * HW_ * HD_;
  const unsigned short* kp = k_s + (size_t)bh * KVP_ * HD_;
  const unsigned short* vp = vT + (size_t)bh * HD_ * KVP_;
  unsigned short* Pw = Pb[wid];

  const int srow = lane >> 3;
  const int schunk = (lane & 7) ^ srow;

  // one stage = exactly 2 gload_lds per wave (waves 0-3: K, waves 4-7: V)
  auto stage = [&](int bufi, int kk) {
    if (wid < 4) {
#pragma unroll
      for (int jj = 0; jj < 2; ++jj)
        GLD_LDS16(kp + (size_t)(kk + wid * 16 + jj * 8 + srow) * HD_ + schunk * 8,
                  &Ks[bufi][(wid * 2 + jj) * 512]);
    } else {
#pragma unroll
      for (int jj = 0; jj < 2; ++jj)
        GLD_LDS16(vp + (size_t)((wid - 4) * 16 + jj * 8 + srow) * KVP_ + kk + schunk * 8,
                  &Vs[bufi][((wid - 4) * 2 + jj) * 512]);
    }
  };

  int ro[4], koff[2];
#pragma unroll
  for (int t = 0; t < 4; ++t) ro[t] = (t * 16 + lr) * 64;
#pragma unroll
  for (int ks = 0; ks < 2; ++ks) koff[ks] = ((ks * 4 + lg) ^ (lr & 7)) * 8;

  bf16x8 qf[2];
#pragma unroll
  for (int ks = 0; ks < 2; ++ks)
    qf[ks] = *(const bf16x8*)&qp[(size_t)(q0 + lr) * HD_ + ks * 32 + lg * 8];

  f32x4 acc[4] = {};
  float lrun = 0.f;

  // prologue: pin issue order so counted vmcnt at loop head is exact
  __builtin_amdgcn_sched_barrier(0);
  stage(0, 0);
  __builtin_amdgcn_sched_barrier(0);
  stage(1, 64);
  __builtin_amdgcn_sched_barrier(0);

  int cur = 0;
  for (int it = 0; it < 17; ++it) {
    // my stage(it) loads landed; stage(it+1) stays in flight across the barrier
    asm volatile("s_waitcnt vmcnt(2)" ::: "memory");
    __builtin_amdgcn_sched_barrier(0);
    __builtin_amdgcn_s_barrier();
    __builtin_amdgcn_sched_barrier(0);
    attn_tile64<false>(Ks[cur], Vs[cur], 64, qf, Pw, lr, lg, ro, koff, lrun, acc);
    asm volatile("s_waitcnt lgkmcnt(0)" ::: "memory");
    __builtin_amdgcn_sched_barrier(0);
    __builtin_amdgcn_s_barrier();
    __builtin_amdgcn_sched_barrier(0);
    if (it < 16) stage(cur, (it + 2) * 64);
    cur ^= 1;
  }
  // final tile: full drain, masked at KV_
  asm volatile("s_waitcnt vmcnt(0)" ::: "memory");
  __builtin_amdgcn_sched_barrier(0);
  __builtin_amdgcn_s_barrier();
  __builtin_amdgcn_sched_barrier(0);
  attn_tile64<true>(Ks[cur], Vs[cur], KV_ - 17 * 64, qf, Pw, lr, lg, ro, koff, lrun, acc);

  const int bb = bh >> 3, head = bh & 7;
  const float inv = 1.f / lrun;
  const int qi = q0 + lr;
#pragma unroll
  for (int dt = 0; dt < 4; ++dt) {
    u16x4 o;
#pragma unroll
    for (int r = 0; r < 4; ++r) o[r] = f2bf(acc[dt][r] * inv);
    *(u16x4*)&at_s[((size_t)bb * HW_ + qi) * DIM_ + head * HD_ + dt * 16 + lg * 4] = o;
  }
}

extern "C" void kernel_launch(void* const* d_in, const int* in_sizes, int n_in,
                              void* d_out, int out_size, void* d_ws, size_t ws_size,
                              hipStream_t stream) {
  (void)in_sizes; (void)n_in; (void)out_size; (void)ws_size;
  const float* x      = (const float*)d_in[0];
  const float* ctx    = (const float*)d_in[1];
  const float* gng    = (const float*)d_in[2];
  const float* gnb    = (const float*)d_in[3];
  const float* qkv_w  = (const float*)d_in[4];
  const float* qkv_b  = (const float*)d_in[5];
  const float* ckv_w  = (const float*)d_in[6];
  const float* ckv_b  = (const float*)d_in[7];
  const float* proj_w = (const float*)d_in[8];
  const float* proj_b = (const float*)d_in[9];
  float* out = (float*)d_out;

  char* ws = (char*)d_ws;
  size_t off = 0;
  auto alloc = [&](size_t bytes) {
    char* p = ws + off;
    off = (off + bytes + 255) & ~(size_t)255;
    return p;
  };
  unsigned short* xn_t    = (unsigned short*)alloc((size_t)B_ * HW_ * DIM_ * 2);
  unsigned short* ctx_bf  = (unsigned short*)alloc((size_t)B_ * LP_ * CTX_ * 2);
  unsigned short* qkvw_bf = (unsigned short*)alloc((size_t)3 * DIM_ * DIM_ * 2);
  unsigned short* ckvw_bf = (unsigned short*)alloc((size_t)2 * DIM_ * CTX_ * 2);
  unsigned short* projw_bf= (unsigned short*)alloc((size_t)DIM_ * DIM_ * 2);
  unsigned short* q_s     = (unsigned short*)alloc((size_t)64 * HW_ * HD_ * 2);
  unsigned short* k_s     = (unsigned short*)alloc((size_t)64 * KVP_ * HD_ * 2);
  unsigned short* vT      = (unsigned short*)alloc((size_t)64 * HD_ * KVP_ * 2);
  unsigned short* at_s    = (unsigned short*)alloc((size_t)B_ * HW_ * DIM_ * 2);

  conv_w_k<<<1792, 256, 0, stream>>>(qkv_w, ckv_w, proj_w, qkvw_bf, ckvw_bf, projw_bf);
  conv_ctx_k<<<480, 256, 0, stream>>>(ctx, ctx_bf);
  gnorm_k<<<256, 256, 0, stream>>>(x, gng, gnb, xn_t);
  pad_zero_k<<<816, 256, 0, stream>>>(k_s, vT);
  gemm_qkv_ckv_k<<<848, 256, 0, stream>>>(xn_t, qkvw_bf, ctx_bf, ckvw_bf,
                                          qkv_b, ckv_b, q_s, k_s, vT);
  attn_k<<<512, 512, 0, stream>>>(q_s, k_s, vT, at_s);
  gemm_proj_k<<<512, 256, 0, stream>>>(projw_bf, at_s, proj_b, x, out);
}

// Round 11
// 75.665 us; speedup vs baseline: 1.7086x; 1.1678x over previous
//
#include <hip/hip_runtime.h>

#define B_ 8
#define DIM_ 512
#define HEADS_ 8
#define HD_ 64
#define HW_ 1024
#define L_ 77
#define LP_ 80
#define CTX_ 768
#define KV_ 1101
#define KVP_ 1152
#define NPAD_ 51
// internal KV order: self-attn rows [0,1024), context rows [1024,1101), pad [1101,1152)
#define CTX0_ 1024
// sqrt(SCALE^2 * log2(e)) folded into both q and k: 64^-0.25 * sqrt(1.4426950409)
#define SC_QK 0.42466089f

typedef __attribute__((ext_vector_type(8))) short bf16x8;
typedef __attribute__((ext_vector_type(4))) float f32x4;
typedef __attribute__((ext_vector_type(4))) unsigned short u16x4;

__device__ __forceinline__ unsigned short f2bf(float f) {
  union { float f; unsigned int u; } c; c.f = f;
  unsigned int u = c.u;
  return (unsigned short)((u + 0x7fffu + ((u >> 16) & 1u)) >> 16);
}
__device__ __forceinline__ float bf2f(unsigned short h) {
  union { unsigned int u; float f; } c; c.u = ((unsigned int)h) << 16;
  return c.f;
}

#define GLD_LDS16(gsrc, ldst) \
  __builtin_amdgcn_global_load_lds((const __attribute__((address_space(1))) void*)(gsrc), \
                                   (__attribute__((address_space(3))) void*)(ldst), 16, 0, 0)

// ---------------- prep: weight converts + ctx convert + KV pad zero (one launch) ----------------
__global__ __launch_bounds__(256) void prep_k(const float* __restrict__ qkv_w,
                                              const float* __restrict__ ckv_w,
                                              const float* __restrict__ proj_w,
                                              const float* __restrict__ ctx,
                                              unsigned short* __restrict__ dq,
                                              unsigned short* __restrict__ dc,
                                              unsigned short* __restrict__ dp,
                                              unsigned short* __restrict__ ctx_bf,
                                              unsigned short* __restrict__ k_s,
                                              unsigned short* __restrict__ vT) {
  int bid = blockIdx.x;
  int tid = threadIdx.x;
  if (bid < 1792) {
    // f32->bf16 weight converts
    int i = bid * 256 + tid;
    const float* src;
    unsigned short* dst;
    int off;
    if (i < 196608) { src = qkv_w; dst = dq; off = i; }                 // 3*512*512/4
    else if (i < 393216) { src = ckv_w; dst = dc; off = i - 196608; }   // 2*512*768/4
    else { src = proj_w; dst = dp; off = i - 393216; }                  // 512*512/4
    float4 v = *(const float4*)(src + (size_t)off * 4);
    u16x4 o;
    o[0] = f2bf(v.x); o[1] = f2bf(v.y); o[2] = f2bf(v.z); o[3] = f2bf(v.w);
    *(u16x4*)(dst + (size_t)off * 4) = o;
  } else if (bid < 2272) {
    // ctx f32 -> bf16, padded L_->LP_
    int i = (bid - 1792) * 256 + tid;
    int idx = i * 4;
    int b = idx / (LP_ * CTX_);
    int rem = idx - b * (LP_ * CTX_);
    int l = rem / CTX_;
    int c = rem - l * CTX_;
    float4 v = make_float4(0.f, 0.f, 0.f, 0.f);
    if (l < L_) v = *(const float4*)&ctx[((size_t)b * L_ + l) * CTX_ + c];
    u16x4 o;
    o[0] = f2bf(v.x); o[1] = f2bf(v.y); o[2] = f2bf(v.z); o[3] = f2bf(v.w);
    *(u16x4*)(ctx_bf + idx) = o;
  } else {
    // zero KV pad rows [KV_, KVP_) — K zeros make S_pad=0 -> P_pad=1 (corrected
    // by -NPAD_ in the attn denominator); V zeros keep the numerator exact.
    int i = (bid - 2272) * 256 + tid;
    int bh = i / (NPAD_ * 64);
    int rem = i - bh * (NPAD_ * 64);
    int row = KV_ + rem / 64;
    int d = rem & 63;
    k_s[((size_t)bh * KVP_ + row) * HD_ + d] = 0;
    vT[((size_t)bh * HD_ + d) * KVP_ + row] = 0;
  }
}

// ---------------- groupnorm (fused stats+normalize+transpose) ----------------
__global__ __launch_bounds__(256) void gnorm_k(const float* __restrict__ x,
                                               const float* __restrict__ gamma,
                                               const float* __restrict__ beta,
                                               unsigned short* __restrict__ xn_t) {
  __shared__ unsigned short xs[16][1032];
  __shared__ float red[8];
  const int tid = threadIdx.x;
  const int b = blockIdx.x >> 5, g = blockIdx.x & 31;
  const float* xp = x + ((size_t)b * DIM_ + g * 16) * HW_;
  float sum = 0.f, ssq = 0.f;
#pragma unroll
  for (int i = 0; i < 16; ++i) {
    float4 v = *(const float4*)&xp[i * HW_ + tid * 4];
    sum += v.x + v.y + v.z + v.w;
    ssq += v.x * v.x + v.y * v.y + v.z * v.z + v.w * v.w;
    xs[i][tid * 4 + 0] = f2bf(v.x);
    xs[i][tid * 4 + 1] = f2bf(v.y);
    xs[i][tid * 4 + 2] = f2bf(v.z);
    xs[i][tid * 4 + 3] = f2bf(v.w);
  }
#pragma unroll
  for (int off = 32; off >= 1; off >>= 1) {
    sum += __shfl_xor(sum, off, 64);
    ssq += __shfl_xor(ssq, off, 64);
  }
  if ((tid & 63) == 0) { red[(tid >> 6) * 2] = sum; red[(tid >> 6) * 2 + 1] = ssq; }
  __syncthreads();
  sum = red[0] + red[2] + red[4] + red[6];
  ssq = red[1] + red[3] + red[5] + red[7];
  float mu = sum * (1.f / 16384.f);
  float rstd = rsqrtf(ssq * (1.f / 16384.f) - mu * mu + 1e-5f);
  float a[16], c[16];
#pragma unroll
  for (int ci = 0; ci < 16; ++ci) {
    float gm = gamma[g * 16 + ci], bt = beta[g * 16 + ci];
    a[ci] = rstd * gm;
    c[ci] = bt - mu * rstd * gm;
  }
#pragma unroll
  for (int t = 0; t < 4; ++t) {
    int hw = tid + t * 256;
    unsigned short tmp[16];
#pragma unroll
    for (int ci = 0; ci < 16; ++ci)
      tmp[ci] = f2bf(bf2f(xs[ci][hw]) * a[ci] + c[ci]);
    unsigned int w[8];
#pragma unroll
    for (int j = 0; j < 8; ++j) w[j] = (unsigned int)tmp[2 * j] | ((unsigned int)tmp[2 * j + 1] << 16);
    unsigned short* dptr = &xn_t[((size_t)b * HW_ + hw) * DIM_ + g * 16];
    *(uint4*)dptr = make_uint4(w[0], w[1], w[2], w[3]);
    *(uint4*)(dptr + 8) = make_uint4(w[4], w[5], w[6], w[7]);
  }
}

// ---------------- GEMM body: C[m][n] = sum_k A[m][k]*Bt[n][k] ----------------
// BM x BN tiles, 2x2 waves, dbuf LDS with COUNTED vmcnt, T2 XOR chunk-swizzle.
// MODE 0: qkv -> LDS-transpose epilogue, coalesced q/k/v stores (+bias, SC_QK)
// MODE 1: ckv -> scalar scatter to k_s/vT at rows 1024+l
// MODE 2: proj -> out = acc + bias[row] + x (residual), coalesced f32
template <int MODE, int BM, int BN>
__device__ __forceinline__ void gemm_body(int bid,
                                          const unsigned short* __restrict__ A,
                                          const unsigned short* __restrict__ Bt,
                                          int M, int N, int K,
                                          const float* __restrict__ bias,
                                          unsigned short* __restrict__ out_q,
                                          unsigned short* __restrict__ out_k,
                                          unsigned short* __restrict__ out_v,
                                          const float* __restrict__ xres,
                                          float* __restrict__ outf,
                                          unsigned short* sm) {
  constexpr int MR = BM / 32;
  constexpr int NR = BN / 32;
  constexpr int SLOADS = BM / 32 + BN / 32;  // gload_lds per thread per stage
  unsigned short* As0 = sm;                  // [2][BM*64]
  unsigned short* Bs0 = sm + 2 * BM * 64;    // [2][BN*64]
  const int tid = threadIdx.x;
  const int wid = tid >> 6, lane = tid & 63;
  const int lr = lane & 15, lg = lane >> 4;
  const int ntn = N / BN;
  const int tm = bid / ntn, tn = bid - tm * ntn;
  const int m0 = tm * BM, n0 = tn * BN;
  const int wr = wid >> 1, wc = wid & 1;
  f32x4 acc[MR][NR] = {};
  const int nkt = K >> 6;

  auto stage = [&](int bi, int kk) {
#pragma unroll
    for (int i = 0; i < BM / 32; ++i) {
      int c = i * 256 + tid;
      int row = c >> 3, ch = (c & 7) ^ (row & 7);
      GLD_LDS16(A + (size_t)(m0 + row) * K + kk + ch * 8,
                As0 + (size_t)bi * BM * 64 + (size_t)(i * 256 + wid * 64) * 8);
    }
#pragma unroll
    for (int i = 0; i < BN / 32; ++i) {
      int c = i * 256 + tid;
      int row = c >> 3, ch = (c & 7) ^ (row & 7);
      GLD_LDS16(Bt + (size_t)(n0 + row) * K + kk + ch * 8,
                Bs0 + (size_t)bi * BN * 64 + (size_t)(i * 256 + wid * 64) * 8);
    }
  };

  // prologue: pin issue order so the counted vmcnt is exact
  __builtin_amdgcn_sched_barrier(0);
  stage(0, 0);
  __builtin_amdgcn_sched_barrier(0);
  if (nkt > 1) stage(1, 64);
  __builtin_amdgcn_sched_barrier(0);

  for (int kt = 0; kt < nkt; ++kt) {
    // stage(kt) landed; stage(kt+1) stays in flight across the barrier
    if (kt < nkt - 1) {
      if constexpr (SLOADS == 8)      asm volatile("s_waitcnt vmcnt(8)" ::: "memory");
      else if constexpr (SLOADS == 6) asm volatile("s_waitcnt vmcnt(6)" ::: "memory");
      else                            asm volatile("s_waitcnt vmcnt(0)" ::: "memory");
    } else {
      asm volatile("s_waitcnt vmcnt(0)" ::: "memory");
    }
    __builtin_amdgcn_sched_barrier(0);
    __builtin_amdgcn_s_barrier();
    __builtin_amdgcn_sched_barrier(0);
    const unsigned short* Ab = As0 + (kt & 1) * BM * 64;
    const unsigned short* Bb = Bs0 + (kt & 1) * BN * 64;
#pragma unroll
    for (int ks = 0; ks < 2; ++ks) {
      bf16x8 af[MR], bf[NR];
#pragma unroll
      for (int mi = 0; mi < MR; ++mi)
        af[mi] = *(const bf16x8*)&Ab[(wr * (BM / 2) + mi * 16 + lr) * 64 +
                                     (((ks * 4 + lg) ^ (lr & 7)) * 8)];
#pragma unroll
      for (int nj = 0; nj < NR; ++nj)
        bf[nj] = *(const bf16x8*)&Bb[(wc * (BN / 2) + nj * 16 + lr) * 64 +
                                     (((ks * 4 + lg) ^ (lr & 7)) * 8)];
#pragma unroll
      for (int mi = 0; mi < MR; ++mi)
#pragma unroll
        for (int nj = 0; nj < NR; ++nj)
          acc[mi][nj] = __builtin_amdgcn_mfma_f32_16x16x32_bf16(af[mi], bf[nj], acc[mi][nj], 0, 0, 0);
    }
    asm volatile("s_waitcnt lgkmcnt(0)" ::: "memory");
    __builtin_amdgcn_sched_barrier(0);
    __builtin_amdgcn_s_barrier();
    __builtin_amdgcn_sched_barrier(0);
    if (kt + 2 < nkt) stage(kt & 1, (kt + 2) << 6);
  }

  if constexpr (MODE == 0) {
    const int which = n0 >> 9;         // uniform per block: 0=q 1=k 2=v
    const int bb = m0 >> 10;
    const int qibase = m0 & 1023;
    if (which == 2) {
      // transpose v through LDS: logical [col 128][qi-chunk 32] of uint2 (4 bf16)
      uint2* Vt = (uint2*)sm;
#pragma unroll
      for (int mi = 0; mi < MR; ++mi) {
#pragma unroll
        for (int nj = 0; nj < NR; ++nj) {
          int col = wc * 64 + nj * 16 + lr;
          float b = bias[n0 + col];
          unsigned int w0, w1;
          float v0 = acc[mi][nj][0] + b, v1 = acc[mi][nj][1] + b;
          float v2 = acc[mi][nj][2] + b, v3 = acc[mi][nj][3] + b;
          asm("v_cvt_pk_bf16_f32 %0, %1, %2" : "=v"(w0) : "v"(v0), "v"(v1));
          asm("v_cvt_pk_bf16_f32 %0, %1, %2" : "=v"(w1) : "v"(v2), "v"(v3));
          int chunk = (wr * 16 + mi * 4 + lg) ^ (lr * 2);
          Vt[col * 32 + chunk] = make_uint2(w0, w1);
        }
      }
      __syncthreads();
#pragma unroll
      for (int it = 0; it < 8; ++it) {
        int col = wid * 32 + it * 4 + lg;
        uint4 val = *(uint4*)&Vt[col * 32 + ((lr * 2) ^ ((col & 15) * 2))];
        int colg = n0 + col;
        int head = (colg >> 6) & 7, d = colg & 63;
        *(uint4*)&out_v[(((size_t)bb * HEADS_ + head) * HD_ + d) * KVP_ + qibase + lr * 8] = val;
      }
    } else {
      // q/k: [qi 128][col 128 (+4 pad)] in LDS, then coalesced 16B row stores
      unsigned short* Tq = sm;
#pragma unroll
      for (int mi = 0; mi < MR; ++mi) {
#pragma unroll
        for (int nj = 0; nj < NR; ++nj) {
          int col = wc * 64 + nj * 16 + lr;
          float b = bias[n0 + col];
          int qr = wr * 64 + mi * 16 + lg * 4;
#pragma unroll
          for (int r = 0; r < 4; ++r)
            Tq[(qr + r) * 132 + col] = f2bf((acc[mi][nj][r] + b) * SC_QK);
        }
      }
      __syncthreads();
#pragma unroll
      for (int it = 0; it < 8; ++it) {
        int qi = wid * 32 + it * 4 + lg;
        uint2 lo = *(uint2*)&Tq[qi * 132 + lr * 8];
        uint2 hi = *(uint2*)&Tq[qi * 132 + lr * 8 + 4];
        uint4 val = make_uint4(lo.x, lo.y, hi.x, hi.y);
        int colg = n0 + lr * 8;
        int head = (colg >> 6) & 7, d = colg & 63;
        size_t bh = (size_t)bb * HEADS_ + head;
        if (which == 0)
          *(uint4*)&out_q[(bh * HW_ + qibase + qi) * HD_ + d] = val;
        else
          *(uint4*)&out_k[(bh * KVP_ + qibase + qi) * HD_ + d] = val;
      }
    }
  } else {
#pragma unroll
    for (int mi = 0; mi < MR; ++mi) {
#pragma unroll
      for (int nj = 0; nj < NR; ++nj) {
#pragma unroll
        for (int r = 0; r < 4; ++r) {
          int row = m0 + wr * (BM / 2) + mi * 16 + lg * 4 + r;
          int col = n0 + wc * (BN / 2) + nj * 16 + lr;
          float v = acc[mi][nj][r];
          if (MODE == 1) {
            int bb = row / LP_, l = row - bb * LP_;
            if (l < L_) {
              v += bias[col];
              int which = col >> 9, head = (col >> 6) & 7, d = col & 63;
              size_t bh = (size_t)bb * HEADS_ + head;
              if (which == 0) out_k[(bh * KVP_ + CTX0_ + l) * HD_ + d] = f2bf(v * SC_QK);
              else            out_v[(bh * HD_ + d) * KVP_ + CTX0_ + l] = f2bf(v);
            }
          } else {
            size_t idx = (size_t)(col >> 10) * (DIM_ * HW_) + (size_t)row * HW_ + (col & 1023);
            outf[idx] = v + bias[row] + xres[idx];
          }
        }
      }
    }
  }
}

// fused ckv (blocks 0..79, 64x128 tiles, dispatched FIRST) + qkv (80..847, XCD-swizzled)
__global__ __launch_bounds__(256, 2) void gemm_qkv_ckv_k(
    const unsigned short* __restrict__ xn_t, const unsigned short* __restrict__ qkvw,
    const unsigned short* __restrict__ ctx_bf, const unsigned short* __restrict__ ckvw,
    const float* __restrict__ qkv_b, const float* __restrict__ ckv_b,
    unsigned short* __restrict__ q_s, unsigned short* __restrict__ k_s,
    unsigned short* __restrict__ vT) {
  __shared__ unsigned short sm[2 * 256 * 64];
  int bid = blockIdx.x;
  if (bid < 80) {
    gemm_body<1, 64, 128>(bid, ctx_bf, ckvw, 640, 1024, 768, ckv_b,
                          nullptr, k_s, vT, nullptr, nullptr, sm);
  } else {
    int b = bid - 80;
    int b2 = (b & 7) * 96 + (b >> 3);
    gemm_body<0, 128, 128>(b2, xn_t, qkvw, 8192, 1536, 512, qkv_b,
                           q_s, k_s, vT, nullptr, nullptr, sm);
  }
}

__global__ __launch_bounds__(256, 2) void gemm_proj_k(
    const unsigned short* __restrict__ projw, const unsigned short* __restrict__ at_s,
    const float* __restrict__ proj_b, const float* __restrict__ x,
    float* __restrict__ out) {
  __shared__ unsigned short sm[2 * 192 * 64];
  gemm_body<2, 64, 128>(blockIdx.x, projw, at_s, 512, 8192, 512, proj_b,
                        nullptr, nullptr, nullptr, x, out, sm);
}

// ---------------- flash attention: 8-wave blocks, no-max softmax, MFMA row-sum ----------------
// p = exp2(S) directly (exact after /sum); row-sum computed on the MFMA pipe via
// lsum = mfma(ones, P); K/V pad rows are zero -> P_pad = 1, corrected by -NPAD_.
#define PSTRIDE 72

__device__ __forceinline__ void attn_tile64(const unsigned short* __restrict__ Ksb,
                                            const unsigned short* __restrict__ Vsb,
                                            const bf16x8 (&qf)[2], const bf16x8 ones,
                                            unsigned short* __restrict__ Pw,
                                            int lr, int lg,
                                            const int (&ro)[4], const int (&koff)[2],
                                            f32x4& lacc, f32x4 (&acc)[4]) {
  f32x4 st[4] = {};
  __builtin_amdgcn_s_setprio(1);
#pragma unroll
  for (int ks = 0; ks < 2; ++ks) {
    bf16x8 kf[4];
#pragma unroll
    for (int t = 0; t < 4; ++t)
      kf[t] = *(const bf16x8*)&Ksb[ro[t] + koff[ks]];
#pragma unroll
    for (int t = 0; t < 4; ++t)
      st[t] = __builtin_amdgcn_mfma_f32_16x16x32_bf16(kf[t], qf[ks], st[t], 0, 0, 0);
  }
  __builtin_amdgcn_s_setprio(0);
  // p = exp2(S), raw v_exp_f32 (inputs bounded, no denorm fixup needed)
#pragma unroll
  for (int t = 0; t < 4; ++t)
#pragma unroll
    for (int r = 0; r < 4; ++r) st[t][r] = __builtin_amdgcn_exp2f(st[t][r]);
  // pack P^T -> [q=lr][k] LDS
#pragma unroll
  for (int t = 0; t < 4; ++t) {
    unsigned int w0, w1;
    asm("v_cvt_pk_bf16_f32 %0, %1, %2" : "=v"(w0) : "v"(st[t][0]), "v"(st[t][1]));
    asm("v_cvt_pk_bf16_f32 %0, %1, %2" : "=v"(w1) : "v"(st[t][2]), "v"(st[t][3]));
    *(uint2*)&Pw[lr * PSTRIDE + t * 16 + lg * 4] = make_uint2(w0, w1);
  }
  // PV + row-sum: O^T[d][q] += V^T[d][k]·P[q][k];  lsum[q] += 1·P[q][k]
#pragma unroll
  for (int ks = 0; ks < 2; ++ks) {
    bf16x8 pb = *(const bf16x8*)&Pw[lr * PSTRIDE + ks * 32 + lg * 8];
    __builtin_amdgcn_s_setprio(1);
    lacc = __builtin_amdgcn_mfma_f32_16x16x32_bf16(ones, pb, lacc, 0, 0, 0);
#pragma unroll
    for (int dt = 0; dt < 4; ++dt) {
      bf16x8 vf = *(const bf16x8*)&Vsb[ro[dt] + koff[ks]];
      acc[dt] = __builtin_amdgcn_mfma_f32_16x16x32_bf16(vf, pb, acc[dt], 0, 0, 0);
    }
    __builtin_amdgcn_s_setprio(0);
  }
}

__global__ __launch_bounds__(512, 4) void attn_k(const unsigned short* __restrict__ q_s,
                                                 const unsigned short* __restrict__ k_s,
                                                 const unsigned short* __restrict__ vT,
                                                 unsigned short* __restrict__ at_s) {
  __shared__ unsigned short Ks[2][4096];
  __shared__ unsigned short Vs[2][4096];
  __shared__ unsigned short Pb[8][16 * PSTRIDE];
  const int tid = threadIdx.x;
  const int wid = tid >> 6, lane = tid & 63;
  const int lr = lane & 15, lg = lane >> 4;
  // grid = 512: 64 bh x 8 qtiles of 128 q; XCD-bijective swizzle
  const int bidx = blockIdx.x;
  const int xcd = bidx & 7, idx = bidx >> 3;
  const int bh = xcd + 8 * (idx >> 3);
  const int qt = idx & 7;
  const int q0 = qt * 128 + wid * 16;   // one 16-q col per wave
  const unsigned short* qp = q_s + (size_t)bh * HW_ * HD_;
  const unsigned short* kp = k_s + (size_t)bh * KVP_ * HD_;
  const unsigned short* vp = vT + (size_t)bh * HD_ * KVP_;
  unsigned short* Pw = Pb[wid];

  const int srow = lane >> 3;
  const int schunk = (lane & 7) ^ srow;

  // one stage = exactly 2 gload_lds per wave (waves 0-3: K, waves 4-7: V)
  auto stage = [&](int bufi, int kk) {
    if (wid < 4) {
#pragma unroll
      for (int jj = 0; jj < 2; ++jj)
        GLD_LDS16(kp + (size_t)(kk + wid * 16 + jj * 8 + srow) * HD_ + schunk * 8,
                  &Ks[bufi][(wid * 2 + jj) * 512]);
    } else {
#pragma unroll
      for (int jj = 0; jj < 2; ++jj)
        GLD_LDS16(vp + (size_t)((wid - 4) * 16 + jj * 8 + srow) * KVP_ + kk + schunk * 8,
                  &Vs[bufi][((wid - 4) * 2 + jj) * 512]);
    }
  };

  int ro[4], koff[2];
#pragma unroll
  for (int t = 0; t < 4; ++t) ro[t] = (t * 16 + lr) * 64;
#pragma unroll
  for (int ks = 0; ks < 2; ++ks) koff[ks] = ((ks * 4 + lg) ^ (lr & 7)) * 8;

  bf16x8 qf[2];
#pragma unroll
  for (int ks = 0; ks < 2; ++ks)
    qf[ks] = *(const bf16x8*)&qp[(size_t)(q0 + lr) * HD_ + ks * 32 + lg * 8];

  bf16x8 ones;
#pragma unroll
  for (int j = 0; j < 8; ++j) ones[j] = (short)0x3F80;  // bf16 1.0

  f32x4 acc[4] = {};
  f32x4 lacc = {};

  // prologue: pin issue order so counted vmcnt at loop head is exact
  __builtin_amdgcn_sched_barrier(0);
  stage(0, 0);
  __builtin_amdgcn_sched_barrier(0);
  stage(1, 64);
  __builtin_amdgcn_sched_barrier(0);

  int cur = 0;
  for (int it = 0; it < 17; ++it) {
    // my stage(it) loads landed; stage(it+1) stays in flight across the barrier
    asm volatile("s_waitcnt vmcnt(2)" ::: "memory");
    __builtin_amdgcn_sched_barrier(0);
    __builtin_amdgcn_s_barrier();
    __builtin_amdgcn_sched_barrier(0);
    attn_tile64(Ks[cur], Vs[cur], qf, ones, Pw, lr, lg, ro, koff, lacc, acc);
    asm volatile("s_waitcnt lgkmcnt(0)" ::: "memory");
    __builtin_amdgcn_sched_barrier(0);
    __builtin_amdgcn_s_barrier();
    __builtin_amdgcn_sched_barrier(0);
    if (it < 16) stage(cur, (it + 2) * 64);
    cur ^= 1;
  }
  // final tile: full drain
  asm volatile("s_waitcnt vmcnt(0)" ::: "memory");
  __builtin_amdgcn_sched_barrier(0);
  __builtin_amdgcn_s_barrier();
  __builtin_amdgcn_sched_barrier(0);
  attn_tile64(Ks[cur], Vs[cur], qf, ones, Pw, lr, lg, ro, koff, lacc, acc);

  const int bb = bh >> 3, head = bh & 7;
  // denominator: subtract the NPAD_ pad contributions (P_pad = 1.0 exactly)
  const float inv = 1.f / (lacc[0] - (float)NPAD_);
  const int qi = q0 + lr;
#pragma unroll
  for (int dt = 0; dt < 4; ++dt) {
    u16x4 o;
#pragma unroll
    for (int r = 0; r < 4; ++r) o[r] = f2bf(acc[dt][r] * inv);
    *(u16x4*)&at_s[((size_t)bb * HW_ + qi) * DIM_ + head * HD_ + dt * 16 + lg * 4] = o;
  }
}

extern "C" void kernel_launch(void* const* d_in, const int* in_sizes, int n_in,
                              void* d_out, int out_size, void* d_ws, size_t ws_size,
                              hipStream_t stream) {
  (void)in_sizes; (void)n_in; (void)out_size; (void)ws_size;
  const float* x      = (const float*)d_in[0];
  const float* ctx    = (const float*)d_in[1];
  const float* gng    = (const float*)d_in[2];
  const float* gnb    = (const float*)d_in[3];
  const float* qkv_w  = (const float*)d_in[4];
  const float* qkv_b  = (const float*)d_in[5];
  const float* ckv_w  = (const float*)d_in[6];
  const float* ckv_b  = (const float*)d_in[7];
  const float* proj_w = (const float*)d_in[8];
  const float* proj_b = (const float*)d_in[9];
  float* out = (float*)d_out;

  char* ws = (char*)d_ws;
  size_t off = 0;
  auto alloc = [&](size_t bytes) {
    char* p = ws + off;
    off = (off + bytes + 255) & ~(size_t)255;
    return p;
  };
  unsigned short* xn_t    = (unsigned short*)alloc((size_t)B_ * HW_ * DIM_ * 2);
  unsigned short* ctx_bf  = (unsigned short*)alloc((size_t)B_ * LP_ * CTX_ * 2);
  unsigned short* qkvw_bf = (unsigned short*)alloc((size_t)3 * DIM_ * DIM_ * 2);
  unsigned short* ckvw_bf = (unsigned short*)alloc((size_t)2 * DIM_ * CTX_ * 2);
  unsigned short* projw_bf= (unsigned short*)alloc((size_t)DIM_ * DIM_ * 2);
  unsigned short* q_s     = (unsigned short*)alloc((size_t)64 * HW_ * HD_ * 2);
  unsigned short* k_s     = (unsigned short*)alloc((size_t)64 * KVP_ * HD_ * 2);
  unsigned short* vT      = (unsigned short*)alloc((size_t)64 * HD_ * KVP_ * 2);
  unsigned short* at_s    = (unsigned short*)alloc((size_t)B_ * HW_ * DIM_ * 2);

  prep_k<<<3088, 256, 0, stream>>>(qkv_w, ckv_w, proj_w, ctx,
                                   qkvw_bf, ckvw_bf, projw_bf, ctx_bf, k_s, vT);
  gnorm_k<<<256, 256, 0, stream>>>(x, gng, gnb, xn_t);
  gemm_qkv_ckv_k<<<848, 256, 0, stream>>>(xn_t, qkvw_bf, ctx_bf, ckvw_bf,
                                          qkv_b, ckv_b, q_s, k_s, vT);
  attn_k<<<512, 512, 0, stream>>>(q_s, k_s, vT, at_s);
  gemm_proj_k<<<512, 256, 0, stream>>>(projw_bf, at_s, proj_b, x, out);
}

// Round 12
// 74.816 us; speedup vs baseline: 1.7280x; 1.0114x over previous
//
#include <hip/hip_runtime.h>

#define B_ 8
#define DIM_ 512
#define HEADS_ 8
#define HD_ 64
#define HW_ 1024
#define L_ 77
#define LP_ 80
#define CTX_ 768
#define KV_ 1101
#define KVP_ 1152
#define NPAD_ 51
// internal KV order: self-attn rows [0,1024), context rows [1024,1101), pad [1101,1152)
#define CTX0_ 1024
// sqrt(SCALE^2 * log2(e)) folded into both q and k: 64^-0.25 * sqrt(1.4426950409)
#define SC_QK 0.42466089f

typedef __attribute__((ext_vector_type(8))) short bf16x8;
typedef __attribute__((ext_vector_type(4))) float f32x4;
typedef __attribute__((ext_vector_type(4))) unsigned short u16x4;

__device__ __forceinline__ unsigned short f2bf(float f) {
  union { float f; unsigned int u; } c; c.f = f;
  unsigned int u = c.u;
  return (unsigned short)((u + 0x7fffu + ((u >> 16) & 1u)) >> 16);
}
__device__ __forceinline__ float bf2f(unsigned short h) {
  union { unsigned int u; float f; } c; c.u = ((unsigned int)h) << 16;
  return c.f;
}

#define GLD_LDS16(gsrc, ldst) \
  __builtin_amdgcn_global_load_lds((const __attribute__((address_space(1))) void*)(gsrc), \
                                   (__attribute__((address_space(3))) void*)(ldst), 16, 0, 0)

// ---------------- prep: weight converts + ctx convert + KV pad zero (one launch) ----------------
__global__ __launch_bounds__(256) void prep_k(const float* __restrict__ qkv_w,
                                              const float* __restrict__ ckv_w,
                                              const float* __restrict__ proj_w,
                                              const float* __restrict__ ctx,
                                              unsigned short* __restrict__ dq,
                                              unsigned short* __restrict__ dc,
                                              unsigned short* __restrict__ dp,
                                              unsigned short* __restrict__ ctx_bf,
                                              unsigned short* __restrict__ k_s,
                                              unsigned short* __restrict__ vT) {
  int bid = blockIdx.x;
  int tid = threadIdx.x;
  if (bid < 1792) {
    // f32->bf16 weight converts
    int i = bid * 256 + tid;
    const float* src;
    unsigned short* dst;
    int off;
    if (i < 196608) { src = qkv_w; dst = dq; off = i; }                 // 3*512*512/4
    else if (i < 393216) { src = ckv_w; dst = dc; off = i - 196608; }   // 2*512*768/4
    else { src = proj_w; dst = dp; off = i - 393216; }                  // 512*512/4
    float4 v = *(const float4*)(src + (size_t)off * 4);
    u16x4 o;
    o[0] = f2bf(v.x); o[1] = f2bf(v.y); o[2] = f2bf(v.z); o[3] = f2bf(v.w);
    *(u16x4*)(dst + (size_t)off * 4) = o;
  } else if (bid < 2272) {
    // ctx f32 -> bf16, padded L_->LP_
    int i = (bid - 1792) * 256 + tid;
    int idx = i * 4;
    int b = idx / (LP_ * CTX_);
    int rem = idx - b * (LP_ * CTX_);
    int l = rem / CTX_;
    int c = rem - l * CTX_;
    float4 v = make_float4(0.f, 0.f, 0.f, 0.f);
    if (l < L_) v = *(const float4*)&ctx[((size_t)b * L_ + l) * CTX_ + c];
    u16x4 o;
    o[0] = f2bf(v.x); o[1] = f2bf(v.y); o[2] = f2bf(v.z); o[3] = f2bf(v.w);
    *(u16x4*)(ctx_bf + idx) = o;
  } else {
    // zero KV pad rows [KV_, KVP_) — K zeros make S_pad=0 -> P_pad=1 (corrected
    // by -NPAD_ in the attn denominator); V zeros keep the numerator exact.
    int i = (bid - 2272) * 256 + tid;
    int bh = i / (NPAD_ * 64);
    int rem = i - bh * (NPAD_ * 64);
    int row = KV_ + rem / 64;
    int d = rem & 63;
    k_s[((size_t)bh * KVP_ + row) * HD_ + d] = 0;
    vT[((size_t)bh * HD_ + d) * KVP_ + row] = 0;
  }
}

// ---------------- groupnorm (fused stats+normalize+transpose) ----------------
__global__ __launch_bounds__(256) void gnorm_k(const float* __restrict__ x,
                                               const float* __restrict__ gamma,
                                               const float* __restrict__ beta,
                                               unsigned short* __restrict__ xn_t) {
  __shared__ unsigned short xs[16][1032];
  __shared__ float red[8];
  const int tid = threadIdx.x;
  const int b = blockIdx.x >> 5, g = blockIdx.x & 31;
  const float* xp = x + ((size_t)b * DIM_ + g * 16) * HW_;
  float sum = 0.f, ssq = 0.f;
#pragma unroll
  for (int i = 0; i < 16; ++i) {
    float4 v = *(const float4*)&xp[i * HW_ + tid * 4];
    sum += v.x + v.y + v.z + v.w;
    ssq += v.x * v.x + v.y * v.y + v.z * v.z + v.w * v.w;
    xs[i][tid * 4 + 0] = f2bf(v.x);
    xs[i][tid * 4 + 1] = f2bf(v.y);
    xs[i][tid * 4 + 2] = f2bf(v.z);
    xs[i][tid * 4 + 3] = f2bf(v.w);
  }
#pragma unroll
  for (int off = 32; off >= 1; off >>= 1) {
    sum += __shfl_xor(sum, off, 64);
    ssq += __shfl_xor(ssq, off, 64);
  }
  if ((tid & 63) == 0) { red[(tid >> 6) * 2] = sum; red[(tid >> 6) * 2 + 1] = ssq; }
  __syncthreads();
  sum = red[0] + red[2] + red[4] + red[6];
  ssq = red[1] + red[3] + red[5] + red[7];
  float mu = sum * (1.f / 16384.f);
  float rstd = rsqrtf(ssq * (1.f / 16384.f) - mu * mu + 1e-5f);
  float a[16], c[16];
#pragma unroll
  for (int ci = 0; ci < 16; ++ci) {
    float gm = gamma[g * 16 + ci], bt = beta[g * 16 + ci];
    a[ci] = rstd * gm;
    c[ci] = bt - mu * rstd * gm;
  }
#pragma unroll
  for (int t = 0; t < 4; ++t) {
    int hw = tid + t * 256;
    unsigned short tmp[16];
#pragma unroll
    for (int ci = 0; ci < 16; ++ci)
      tmp[ci] = f2bf(bf2f(xs[ci][hw]) * a[ci] + c[ci]);
    unsigned int w[8];
#pragma unroll
    for (int j = 0; j < 8; ++j) w[j] = (unsigned int)tmp[2 * j] | ((unsigned int)tmp[2 * j + 1] << 16);
    unsigned short* dptr = &xn_t[((size_t)b * HW_ + hw) * DIM_ + g * 16];
    *(uint4*)dptr = make_uint4(w[0], w[1], w[2], w[3]);
    *(uint4*)(dptr + 8) = make_uint4(w[4], w[5], w[6], w[7]);
  }
}

// ---------------- GEMM body: C[m][n] = sum_k A[m][k]*Bt[n][k] ----------------
// BM x BN tiles, 2x2 waves, dbuf LDS with COUNTED vmcnt, T2 XOR chunk-swizzle.
// MODE 0: qkv -> LDS-transpose epilogue, coalesced q/k/v stores (+bias, SC_QK)
// MODE 1: ckv -> scalar scatter to k_s/vT at rows 1024+l
// MODE 2: proj -> out = acc + bias[row] + x (residual), coalesced f32
template <int MODE, int BM, int BN>
__device__ __forceinline__ void gemm_body(int bid,
                                          const unsigned short* __restrict__ A,
                                          const unsigned short* __restrict__ Bt,
                                          int M, int N, int K,
                                          const float* __restrict__ bias,
                                          unsigned short* __restrict__ out_q,
                                          unsigned short* __restrict__ out_k,
                                          unsigned short* __restrict__ out_v,
                                          const float* __restrict__ xres,
                                          float* __restrict__ outf,
                                          unsigned short* sm) {
  constexpr int MR = BM / 32;
  constexpr int NR = BN / 32;
  constexpr int SLOADS = BM / 32 + BN / 32;  // gload_lds per thread per stage
  unsigned short* As0 = sm;                  // [2][BM*64]
  unsigned short* Bs0 = sm + 2 * BM * 64;    // [2][BN*64]
  const int tid = threadIdx.x;
  const int wid = tid >> 6, lane = tid & 63;
  const int lr = lane & 15, lg = lane >> 4;
  const int ntn = N / BN;
  const int tm = bid / ntn, tn = bid - tm * ntn;
  const int m0 = tm * BM, n0 = tn * BN;
  const int wr = wid >> 1, wc = wid & 1;
  f32x4 acc[MR][NR] = {};
  const int nkt = K >> 6;

  auto stage = [&](int bi, int kk) {
#pragma unroll
    for (int i = 0; i < BM / 32; ++i) {
      int c = i * 256 + tid;
      int row = c >> 3, ch = (c & 7) ^ (row & 7);
      GLD_LDS16(A + (size_t)(m0 + row) * K + kk + ch * 8,
                As0 + (size_t)bi * BM * 64 + (size_t)(i * 256 + wid * 64) * 8);
    }
#pragma unroll
    for (int i = 0; i < BN / 32; ++i) {
      int c = i * 256 + tid;
      int row = c >> 3, ch = (c & 7) ^ (row & 7);
      GLD_LDS16(Bt + (size_t)(n0 + row) * K + kk + ch * 8,
                Bs0 + (size_t)bi * BN * 64 + (size_t)(i * 256 + wid * 64) * 8);
    }
  };

  // prologue: pin issue order so the counted vmcnt is exact
  __builtin_amdgcn_sched_barrier(0);
  stage(0, 0);
  __builtin_amdgcn_sched_barrier(0);
  if (nkt > 1) stage(1, 64);
  __builtin_amdgcn_sched_barrier(0);

  for (int kt = 0; kt < nkt; ++kt) {
    // stage(kt) landed; stage(kt+1) stays in flight across the barrier
    if (kt < nkt - 1) {
      if constexpr (SLOADS == 8)      asm volatile("s_waitcnt vmcnt(8)" ::: "memory");
      else if constexpr (SLOADS == 6) asm volatile("s_waitcnt vmcnt(6)" ::: "memory");
      else                            asm volatile("s_waitcnt vmcnt(0)" ::: "memory");
    } else {
      asm volatile("s_waitcnt vmcnt(0)" ::: "memory");
    }
    __builtin_amdgcn_sched_barrier(0);
    __builtin_amdgcn_s_barrier();
    __builtin_amdgcn_sched_barrier(0);
    const unsigned short* Ab = As0 + (kt & 1) * BM * 64;
    const unsigned short* Bb = Bs0 + (kt & 1) * BN * 64;
#pragma unroll
    for (int ks = 0; ks < 2; ++ks) {
      bf16x8 af[MR], bf[NR];
#pragma unroll
      for (int mi = 0; mi < MR; ++mi)
        af[mi] = *(const bf16x8*)&Ab[(wr * (BM / 2) + mi * 16 + lr) * 64 +
                                     (((ks * 4 + lg) ^ (lr & 7)) * 8)];
#pragma unroll
      for (int nj = 0; nj < NR; ++nj)
        bf[nj] = *(const bf16x8*)&Bb[(wc * (BN / 2) + nj * 16 + lr) * 64 +
                                     (((ks * 4 + lg) ^ (lr & 7)) * 8)];
#pragma unroll
      for (int mi = 0; mi < MR; ++mi)
#pragma unroll
        for (int nj = 0; nj < NR; ++nj)
          acc[mi][nj] = __builtin_amdgcn_mfma_f32_16x16x32_bf16(af[mi], bf[nj], acc[mi][nj], 0, 0, 0);
    }
    asm volatile("s_waitcnt lgkmcnt(0)" ::: "memory");
    __builtin_amdgcn_sched_barrier(0);
    __builtin_amdgcn_s_barrier();
    __builtin_amdgcn_sched_barrier(0);
    if (kt + 2 < nkt) stage(kt & 1, (kt + 2) << 6);
  }

  if constexpr (MODE == 0) {
    const int which = n0 >> 9;         // uniform per block: 0=q 1=k 2=v
    const int bb = m0 >> 10;
    const int qibase = m0 & 1023;
    if (which == 2) {
      // transpose v through LDS: logical [col 128][qi-chunk 32] of uint2 (4 bf16)
      uint2* Vt = (uint2*)sm;
#pragma unroll
      for (int mi = 0; mi < MR; ++mi) {
#pragma unroll
        for (int nj = 0; nj < NR; ++nj) {
          int col = wc * 64 + nj * 16 + lr;
          float b = bias[n0 + col];
          unsigned int w0, w1;
          float v0 = acc[mi][nj][0] + b, v1 = acc[mi][nj][1] + b;
          float v2 = acc[mi][nj][2] + b, v3 = acc[mi][nj][3] + b;
          asm("v_cvt_pk_bf16_f32 %0, %1, %2" : "=v"(w0) : "v"(v0), "v"(v1));
          asm("v_cvt_pk_bf16_f32 %0, %1, %2" : "=v"(w1) : "v"(v2), "v"(v3));
          int chunk = (wr * 16 + mi * 4 + lg) ^ (lr * 2);
          Vt[col * 32 + chunk] = make_uint2(w0, w1);
        }
      }
      __syncthreads();
#pragma unroll
      for (int it = 0; it < 8; ++it) {
        int col = wid * 32 + it * 4 + lg;
        uint4 val = *(uint4*)&Vt[col * 32 + ((lr * 2) ^ ((col & 15) * 2))];
        int colg = n0 + col;
        int head = (colg >> 6) & 7, d = colg & 63;
        *(uint4*)&out_v[(((size_t)bb * HEADS_ + head) * HD_ + d) * KVP_ + qibase + lr * 8] = val;
      }
    } else {
      // q/k: [qi 128][col 128 (+4 pad)] in LDS, then coalesced 16B row stores
      unsigned short* Tq = sm;
#pragma unroll
      for (int mi = 0; mi < MR; ++mi) {
#pragma unroll
        for (int nj = 0; nj < NR; ++nj) {
          int col = wc * 64 + nj * 16 + lr;
          float b = bias[n0 + col];
          int qr = wr * 64 + mi * 16 + lg * 4;
#pragma unroll
          for (int r = 0; r < 4; ++r)
            Tq[(qr + r) * 132 + col] = f2bf((acc[mi][nj][r] + b) * SC_QK);
        }
      }
      __syncthreads();
#pragma unroll
      for (int it = 0; it < 8; ++it) {
        int qi = wid * 32 + it * 4 + lg;
        uint2 lo = *(uint2*)&Tq[qi * 132 + lr * 8];
        uint2 hi = *(uint2*)&Tq[qi * 132 + lr * 8 + 4];
        uint4 val = make_uint4(lo.x, lo.y, hi.x, hi.y);
        int colg = n0 + lr * 8;
        int head = (colg >> 6) & 7, d = colg & 63;
        size_t bh = (size_t)bb * HEADS_ + head;
        if (which == 0)
          *(uint4*)&out_q[(bh * HW_ + qibase + qi) * HD_ + d] = val;
        else
          *(uint4*)&out_k[(bh * KVP_ + qibase + qi) * HD_ + d] = val;
      }
    }
  } else {
#pragma unroll
    for (int mi = 0; mi < MR; ++mi) {
#pragma unroll
      for (int nj = 0; nj < NR; ++nj) {
#pragma unroll
        for (int r = 0; r < 4; ++r) {
          int row = m0 + wr * (BM / 2) + mi * 16 + lg * 4 + r;
          int col = n0 + wc * (BN / 2) + nj * 16 + lr;
          float v = acc[mi][nj][r];
          if (MODE == 1) {
            int bb = row / LP_, l = row - bb * LP_;
            if (l < L_) {
              v += bias[col];
              int which = col >> 9, head = (col >> 6) & 7, d = col & 63;
              size_t bh = (size_t)bb * HEADS_ + head;
              if (which == 0) out_k[(bh * KVP_ + CTX0_ + l) * HD_ + d] = f2bf(v * SC_QK);
              else            out_v[(bh * HD_ + d) * KVP_ + CTX0_ + l] = f2bf(v);
            }
          } else {
            size_t idx = (size_t)(col >> 10) * (DIM_ * HW_) + (size_t)row * HW_ + (col & 1023);
            outf[idx] = v + bias[row] + xres[idx];
          }
        }
      }
    }
  }
}

// fused ckv (blocks 0..79, 64x128 tiles, dispatched FIRST) + qkv (80..847, XCD-swizzled)
__global__ __launch_bounds__(256, 2) void gemm_qkv_ckv_k(
    const unsigned short* __restrict__ xn_t, const unsigned short* __restrict__ qkvw,
    const unsigned short* __restrict__ ctx_bf, const unsigned short* __restrict__ ckvw,
    const float* __restrict__ qkv_b, const float* __restrict__ ckv_b,
    unsigned short* __restrict__ q_s, unsigned short* __restrict__ k_s,
    unsigned short* __restrict__ vT) {
  __shared__ unsigned short sm[2 * 256 * 64];
  int bid = blockIdx.x;
  if (bid < 80) {
    gemm_body<1, 64, 128>(bid, ctx_bf, ckvw, 640, 1024, 768, ckv_b,
                          nullptr, k_s, vT, nullptr, nullptr, sm);
  } else {
    int b = bid - 80;
    int b2 = (b & 7) * 96 + (b >> 3);
    gemm_body<0, 128, 128>(b2, xn_t, qkvw, 8192, 1536, 512, qkv_b,
                           q_s, k_s, vT, nullptr, nullptr, sm);
  }
}

__global__ __launch_bounds__(256, 2) void gemm_proj_k(
    const unsigned short* __restrict__ projw, const unsigned short* __restrict__ at_s,
    const float* __restrict__ proj_b, const float* __restrict__ x,
    float* __restrict__ out) {
  __shared__ unsigned short sm[2 * 192 * 64];
  gemm_body<2, 64, 128>(blockIdx.x, projw, at_s, 512, 8192, 512, proj_b,
                        nullptr, nullptr, nullptr, x, out, sm);
}

// ---------------- flash attention: 4 waves x 2 q-cols, no-max softmax, MFMA row-sum ----------------
// K/V LDS reads amortized over 2 q-cols per wave (LDS-BW was the R11 binding pipe).
#define PSTRIDE 72

__device__ __forceinline__ void attn_tile64(const unsigned short* __restrict__ Ksb,
                                            const unsigned short* __restrict__ Vsb,
                                            const bf16x8 (&qf)[2][2], const bf16x8 ones,
                                            unsigned short* __restrict__ Pw0,
                                            unsigned short* __restrict__ Pw1,
                                            int lr, int lg,
                                            const int (&ro)[4], const int (&koff)[2],
                                            f32x4 (&lacc)[2], f32x4 (&acc)[2][4]) {
  f32x4 st[2][4] = {};
  __builtin_amdgcn_s_setprio(1);
#pragma unroll
  for (int ks = 0; ks < 2; ++ks) {
    bf16x8 kf[4];
#pragma unroll
    for (int t = 0; t < 4; ++t)
      kf[t] = *(const bf16x8*)&Ksb[ro[t] + koff[ks]];
#pragma unroll
    for (int t = 0; t < 4; ++t) {
      st[0][t] = __builtin_amdgcn_mfma_f32_16x16x32_bf16(kf[t], qf[0][ks], st[0][t], 0, 0, 0);
      st[1][t] = __builtin_amdgcn_mfma_f32_16x16x32_bf16(kf[t], qf[1][ks], st[1][t], 0, 0, 0);
    }
  }
  __builtin_amdgcn_s_setprio(0);
  // p = exp2(S), raw v_exp_f32 (inputs bounded)
#pragma unroll
  for (int c = 0; c < 2; ++c) {
#pragma unroll
    for (int t = 0; t < 4; ++t)
#pragma unroll
      for (int r = 0; r < 4; ++r) st[c][t][r] = __builtin_amdgcn_exp2f(st[c][t][r]);
    unsigned short* Pw = c ? Pw1 : Pw0;
#pragma unroll
    for (int t = 0; t < 4; ++t) {
      unsigned int w0, w1;
      asm("v_cvt_pk_bf16_f32 %0, %1, %2" : "=v"(w0) : "v"(st[c][t][0]), "v"(st[c][t][1]));
      asm("v_cvt_pk_bf16_f32 %0, %1, %2" : "=v"(w1) : "v"(st[c][t][2]), "v"(st[c][t][3]));
      *(uint2*)&Pw[lr * PSTRIDE + t * 16 + lg * 4] = make_uint2(w0, w1);
    }
  }
  // PV + row-sum; V fragments shared across both q-cols
#pragma unroll
  for (int ks = 0; ks < 2; ++ks) {
    bf16x8 pb0 = *(const bf16x8*)&Pw0[lr * PSTRIDE + ks * 32 + lg * 8];
    bf16x8 pb1 = *(const bf16x8*)&Pw1[lr * PSTRIDE + ks * 32 + lg * 8];
    __builtin_amdgcn_s_setprio(1);
    lacc[0] = __builtin_amdgcn_mfma_f32_16x16x32_bf16(ones, pb0, lacc[0], 0, 0, 0);
    lacc[1] = __builtin_amdgcn_mfma_f32_16x16x32_bf16(ones, pb1, lacc[1], 0, 0, 0);
#pragma unroll
    for (int dt = 0; dt < 4; ++dt) {
      bf16x8 vf = *(const bf16x8*)&Vsb[ro[dt] + koff[ks]];
      acc[0][dt] = __builtin_amdgcn_mfma_f32_16x16x32_bf16(vf, pb0, acc[0][dt], 0, 0, 0);
      acc[1][dt] = __builtin_amdgcn_mfma_f32_16x16x32_bf16(vf, pb1, acc[1][dt], 0, 0, 0);
    }
    __builtin_amdgcn_s_setprio(0);
  }
}

__global__ __launch_bounds__(256, 3) void attn_k(const unsigned short* __restrict__ q_s,
                                                 const unsigned short* __restrict__ k_s,
                                                 const unsigned short* __restrict__ vT,
                                                 unsigned short* __restrict__ at_s) {
  __shared__ unsigned short Ks[2][4096];
  __shared__ unsigned short Vs[2][4096];
  __shared__ unsigned short Pb[4][2][16 * PSTRIDE];
  const int tid = threadIdx.x;
  const int wid = tid >> 6, lane = tid & 63;
  const int lr = lane & 15, lg = lane >> 4;
  // grid = 512: 64 bh x 8 qtiles of 128 q; XCD-bijective swizzle
  const int bidx = blockIdx.x;
  const int xcd = bidx & 7, idx = bidx >> 3;
  const int bh = xcd + 8 * (idx >> 3);
  const int qt = idx & 7;
  const int q0 = qt * 128 + wid * 32;   // two 16-q cols per wave
  const unsigned short* qp = q_s + (size_t)bh * HW_ * HD_;
  const unsigned short* kp = k_s + (size_t)bh * KVP_ * HD_;
  const unsigned short* vp = vT + (size_t)bh * HD_ * KVP_;
  unsigned short* Pw0 = Pb[wid][0];
  unsigned short* Pw1 = Pb[wid][1];

  const int srow = lane >> 3;
  const int schunk = (lane & 7) ^ srow;

  // one stage = exactly 4 gload_lds per wave (2 K rows-groups + 2 V)
  auto stage = [&](int bufi, int kk) {
#pragma unroll
    for (int jj = 0; jj < 2; ++jj) {
      GLD_LDS16(kp + (size_t)(kk + wid * 16 + jj * 8 + srow) * HD_ + schunk * 8,
                &Ks[bufi][(wid * 2 + jj) * 512]);
      GLD_LDS16(vp + (size_t)(wid * 16 + jj * 8 + srow) * KVP_ + kk + schunk * 8,
                &Vs[bufi][(wid * 2 + jj) * 512]);
    }
  };

  int ro[4], koff[2];
#pragma unroll
  for (int t = 0; t < 4; ++t) ro[t] = (t * 16 + lr) * 64;
#pragma unroll
  for (int ks = 0; ks < 2; ++ks) koff[ks] = ((ks * 4 + lg) ^ (lr & 7)) * 8;

  bf16x8 qf[2][2];
#pragma unroll
  for (int c = 0; c < 2; ++c)
#pragma unroll
    for (int ks = 0; ks < 2; ++ks)
      qf[c][ks] = *(const bf16x8*)&qp[(size_t)(q0 + c * 16 + lr) * HD_ + ks * 32 + lg * 8];

  bf16x8 ones;
#pragma unroll
  for (int j = 0; j < 8; ++j) ones[j] = (short)0x3F80;  // bf16 1.0

  f32x4 acc[2][4] = {};
  f32x4 lacc[2] = {};

  // prologue: pin issue order so counted vmcnt at loop head is exact
  __builtin_amdgcn_sched_barrier(0);
  stage(0, 0);
  __builtin_amdgcn_sched_barrier(0);
  stage(1, 64);
  __builtin_amdgcn_sched_barrier(0);

  int cur = 0;
  for (int it = 0; it < 17; ++it) {
    // my stage(it) loads landed; stage(it+1) stays in flight across the barrier
    asm volatile("s_waitcnt vmcnt(4)" ::: "memory");
    __builtin_amdgcn_sched_barrier(0);
    __builtin_amdgcn_s_barrier();
    __builtin_amdgcn_sched_barrier(0);
    attn_tile64(Ks[cur], Vs[cur], qf, ones, Pw0, Pw1, lr, lg, ro, koff, lacc, acc);
    asm volatile("s_waitcnt lgkmcnt(0)" ::: "memory");
    __builtin_amdgcn_sched_barrier(0);
    __builtin_amdgcn_s_barrier();
    __builtin_amdgcn_sched_barrier(0);
    if (it < 16) stage(cur, (it + 2) * 64);
    cur ^= 1;
  }
  // final tile: full drain
  asm volatile("s_waitcnt vmcnt(0)" ::: "memory");
  __builtin_amdgcn_sched_barrier(0);
  __builtin_amdgcn_s_barrier();
  __builtin_amdgcn_sched_barrier(0);
  attn_tile64(Ks[cur], Vs[cur], qf, ones, Pw0, Pw1, lr, lg, ro, koff, lacc, acc);

  const int bb = bh >> 3, head = bh & 7;
#pragma unroll
  for (int c = 0; c < 2; ++c) {
    // denominator: subtract the NPAD_ pad contributions (P_pad = 1.0 exactly)
    const float inv = 1.f / (lacc[c][0] - (float)NPAD_);
    const int qi = q0 + c * 16 + lr;
#pragma unroll
    for (int dt = 0; dt < 4; ++dt) {
      u16x4 o;
#pragma unroll
      for (int r = 0; r < 4; ++r) o[r] = f2bf(acc[c][dt][r] * inv);
      *(u16x4*)&at_s[((size_t)bb * HW_ + qi) * DIM_ + head * HD_ + dt * 16 + lg * 4] = o;
    }
  }
}

extern "C" void kernel_launch(void* const* d_in, const int* in_sizes, int n_in,
                              void* d_out, int out_size, void* d_ws, size_t ws_size,
                              hipStream_t stream) {
  (void)in_sizes; (void)n_in; (void)out_size; (void)ws_size;
  const float* x      = (const float*)d_in[0];
  const float* ctx    = (const float*)d_in[1];
  const float* gng    = (const float*)d_in[2];
  const float* gnb    = (const float*)d_in[3];
  const float* qkv_w  = (const float*)d_in[4];
  const float* qkv_b  = (const float*)d_in[5];
  const float* ckv_w  = (const float*)d_in[6];
  const float* ckv_b  = (const float*)d_in[7];
  const float* proj_w = (const float*)d_in[8];
  const float* proj_b = (const float*)d_in[9];
  float* out = (float*)d_out;

  char* ws = (char*)d_ws;
  size_t off = 0;
  auto alloc = [&](size_t bytes) {
    char* p = ws + off;
    off = (off + bytes + 255) & ~(size_t)255;
    return p;
  };
  unsigned short* xn_t    = (unsigned short*)alloc((size_t)B_ * HW_ * DIM_ * 2);
  unsigned short* ctx_bf  = (unsigned short*)alloc((size_t)B_ * LP_ * CTX_ * 2);
  unsigned short* qkvw_bf = (unsigned short*)alloc((size_t)3 * DIM_ * DIM_ * 2);
  unsigned short* ckvw_bf = (unsigned short*)alloc((size_t)2 * DIM_ * CTX_ * 2);
  unsigned short* projw_bf= (unsigned short*)alloc((size_t)DIM_ * DIM_ * 2);
  unsigned short* q_s     = (unsigned short*)alloc((size_t)64 * HW_ * HD_ * 2);
  unsigned short* k_s     = (unsigned short*)alloc((size_t)64 * KVP_ * HD_ * 2);
  unsigned short* vT      = (unsigned short*)alloc((size_t)64 * HD_ * KVP_ * 2);
  unsigned short* at_s    = (unsigned short*)alloc((size_t)B_ * HW_ * DIM_ * 2);

  prep_k<<<3088, 256, 0, stream>>>(qkv_w, ckv_w, proj_w, ctx,
                                   qkvw_bf, ckvw_bf, projw_bf, ctx_bf, k_s, vT);
  gnorm_k<<<256, 256, 0, stream>>>(x, gng, gnb, xn_t);
  gemm_qkv_ckv_k<<<848, 256, 0, stream>>>(xn_t, qkvw_bf, ctx_bf, ckvw_bf,
                                          qkv_b, ckv_b, q_s, k_s, vT);
  attn_k<<<512, 256, 0, stream>>>(q_s, k_s, vT, at_s);
  gemm_proj_k<<<512, 256, 0, stream>>>(projw_bf, at_s, proj_b, x, out);
}